// Round 6
// baseline (724.312 us; speedup 1.0000x reference)
//
#include <hip/hip_runtime.h>

#define DI __device__ __forceinline__

typedef __attribute__((ext_vector_type(8))) short bf16x8;
typedef __attribute__((ext_vector_type(4))) short s16x4;
typedef __attribute__((ext_vector_type(4))) float f32x4;

DI short f2bf(float f) {
  unsigned u = __builtin_bit_cast(unsigned, f);
  u += 0x7FFFu + ((u >> 16) & 1u);
  return (short)(u >> 16);
}

#define WAITVM(N) asm volatile("s_waitcnt vmcnt(" #N ")" ::: "memory")

// Within-64 column permutation used for packed epilogues:
//   position p holds true column c:  p = (c&~63) + (c&15)*4 + ((c>>4)&3)
// Applied consistently to {P cols, vbuf n} (PV contraction) and
// {Wo cols, oT cols} (output-GEMM contraction) -> cancels algebraically.

// ---------------- prep: weights -> bf16 (+ transposed Wk/Wq for G) ----------
__global__ __launch_bounds__(256) void prep_k(
    const float* __restrict__ wq, const float* __restrict__ wk,
    const float* __restrict__ wv, const float* __restrict__ wo,
    short* __restrict__ Wv, short* __restrict__ Wo,
    short* __restrict__ WkT, short* __restrict__ WqT) {
  const int i = blockIdx.x * 256 + threadIdx.x;  // 0..262143
  const float sc = 0.04419417382415922f;         // 1/sqrt(512)
  Wv[i] = f2bf(wv[i]);
  const int c = i & 511;
  const int cp = (c & ~63) | ((c & 15) << 2) | ((c >> 4) & 3);
  Wo[(i & ~511) | cp] = f2bf(wo[i]);             // c-permuted to match oT
  const int tr = (i & 511) * 512 + (i >> 9);
  WkT[tr] = f2bf(wk[i] * sc);   // scale folded into Wk side
  WqT[tr] = f2bf(wq[i]);
}

// ---------------- g0[c'] = s * sum_o wk[o][c'] * bq[o] ----------------------
__global__ __launch_bounds__(256) void g0_k(const float* __restrict__ wk,
                                            const float* __restrict__ bq,
                                            float* __restrict__ g0) {
  const int c = blockIdx.x * 256 + threadIdx.x;  // 0..511
  float acc = 0.f;
#pragma unroll 8
  for (int o = 0; o < 512; ++o) acc += wk[o * 512 + c] * bq[o];
  g0[c] = acc * 0.04419417382415922f;
}

// ---------------- GroupNorm pass 1: per (b,g) mean/rstd ---------------------
__global__ __launch_bounds__(256) void gn_stats(const float* __restrict__ x,
                                                float2* __restrict__ stats) {
  const int bg = blockIdx.x;
  const float4* xg = (const float4*)(x + (size_t)bg * 36864);
  float s = 0.f, q = 0.f;
  for (int i = threadIdx.x; i < 9216; i += 256) {
    float4 v = xg[i];
    s += v.x + v.y + v.z + v.w;
    q += v.x * v.x + v.y * v.y + v.z * v.z + v.w * v.w;
  }
#pragma unroll
  for (int d = 1; d < 64; d <<= 1) { s += __shfl_xor(s, d); q += __shfl_xor(q, d); }
  __shared__ float rs[4], rq[4];
  const int w = threadIdx.x >> 6;
  if ((threadIdx.x & 63) == 0) { rs[w] = s; rq[w] = q; }
  __syncthreads();
  if (threadIdx.x == 0) {
    float S = rs[0] + rs[1] + rs[2] + rs[3];
    float Q = rq[0] + rq[1] + rq[2] + rq[3];
    float mean = S * (1.f / 36864.f);
    float var  = Q * (1.f / 36864.f) - mean * mean;
    float2 o; o.x = mean; o.y = rsqrtf(var + 1e-5f);
    stats[bg] = o;
  }
}

// ---------------- GroupNorm pass 2: normalize + transpose -> yT bf16 --------
__global__ __launch_bounds__(256) void gn_norm_t(
    const float* __restrict__ x, const float2* __restrict__ stats,
    const float* __restrict__ gamma, const float* __restrict__ beta,
    short* __restrict__ yT) {
  __shared__ float ts[64][68];
  const int n0 = blockIdx.x * 64, c0 = blockIdx.y * 64, b = blockIdx.z;
  const int t = threadIdx.x;
  {
    const int cw = t >> 4;
    const int n4 = (t & 15) * 4;
    const float* xb = x + ((size_t)b * 512 + c0) * 2304 + n0;
#pragma unroll
    for (int r4 = 0; r4 < 4; ++r4) {
      const int c = cw + r4 * 16;
      float4 v = *(const float4*)(xb + (size_t)c * 2304 + n4);
      *(float4*)&ts[c][n4] = v;
    }
  }
  __syncthreads();
  {
    const int c4 = t & 15;
    const int nw = t >> 4;
    const int cg = c0 + c4 * 4;
    const float2 ms = stats[b * 32 + (cg >> 4)];
    const float4 gm = *(const float4*)(gamma + cg);
    const float4 bt = *(const float4*)(beta + cg);
    const float a0 = ms.y * gm.x, a1 = ms.y * gm.y, a2 = ms.y * gm.z, a3 = ms.y * gm.w;
    const float d0 = bt.x - ms.x * a0, d1 = bt.y - ms.x * a1,
                d2 = bt.z - ms.x * a2, d3 = bt.w - ms.x * a3;
#pragma unroll
    for (int it = 0; it < 4; ++it) {
      const int no = nw + it * 16;
      const float v0 = ts[c4 * 4 + 0][no], v1 = ts[c4 * 4 + 1][no];
      const float v2 = ts[c4 * 4 + 2][no], v3 = ts[c4 * 4 + 3][no];
      s16x4 o = { f2bf(v0 * a0 + d0), f2bf(v1 * a1 + d1),
                  f2bf(v2 * a2 + d2), f2bf(v3 * a3 + d3) };
      *(s16x4*)(yT + ((size_t)b * 2304 + n0 + no) * 512 + cg) = o;
    }
  }
}

// ---------------- Generic bf16 MFMA GEMM (depth-3 ring) ---------------------
// D[M][N] = A[M][K] * Bt[N][K]^T, 128x128 tile, BK=32.
template <int EPI, bool BIASROW, int LDA, int LDB, int KSTEPS>
__global__ __launch_bounds__(256) void gemm_k(
    const short* __restrict__ A, size_t sA,
    const short* __restrict__ Bt, size_t sB,
    void* __restrict__ Dp, size_t sD,
    const float* __restrict__ bias, const float* __restrict__ resid,
    int N, int tilesM, int boff) {
  __shared__ short As[3][128 * 32];
  __shared__ short Bs[3][128 * 32];
  const int ba = blockIdx.y, bb = blockIdx.y + boff;
  int bx = blockIdx.x;
  bx = (bx & 7) * (int)(gridDim.x >> 3) + (bx >> 3);  // XCD-contiguous; grid.x % 8 == 0
  const int tm = bx % tilesM, tn = bx / tilesM;
  const int row0 = tm * 128, col0 = tn * 128;
  const int tid = threadIdx.x, lane = tid & 63, w = tid >> 6;
  const int lr = lane & 15, lg = lane >> 4;
  const short* Ab = A + (size_t)ba * sA;
  const short* Bb = Bt + (size_t)bb * sB;
  f32x4 acc[4][4];
  const f32x4 zero = {0.f, 0.f, 0.f, 0.f};
#pragma unroll
  for (int i = 0; i < 4; ++i)
#pragma unroll
    for (int j = 0; j < 4; ++j) acc[i][j] = zero;
  const int wrow = (w & 1) * 64, wcol = (w >> 1) * 64;
  const int sw = (lg ^ ((lr >> 1) & 3)) * 8;  // swizzled K-chunk (shorts)

#define GK_STAGE(KS, BUF)                                                      \
  {                                                                            \
    _Pragma("unroll")                                                          \
    for (int j = 0; j < 2; ++j) {                                              \
      const int g = (w * 2 + j) * 64 + lane; /* 16B chunks 0..511 */           \
      const int ko = (KS) * 32 + (((g & 3) ^ ((g >> 3) & 3)) * 8);             \
      const short* ga = Ab + (size_t)(row0 + (g >> 2)) * LDA + ko;             \
      const short* gb = Bb + (size_t)(col0 + (g >> 2)) * LDB + ko;             \
      __builtin_amdgcn_global_load_lds(                                        \
          (__attribute__((address_space(1))) void*)ga,                         \
          (__attribute__((address_space(3))) void*)&As[BUF][(w * 2 + j) * 512],\
          16, 0, 0);                                                           \
      __builtin_amdgcn_global_load_lds(                                        \
          (__attribute__((address_space(1))) void*)gb,                         \
          (__attribute__((address_space(3))) void*)&Bs[BUF][(w * 2 + j) * 512],\
          16, 0, 0);                                                           \
    }                                                                          \
  }

  GK_STAGE(0, 0);
  GK_STAGE(1, 1);
  GK_STAGE(2, 2);
  int cur = 0;
  for (int ks = 0; ks < KSTEPS; ++ks) {
    if (ks + 2 < KSTEPS)      WAITVM(8);   // 3 stages out: oldest landed
    else if (ks + 1 < KSTEPS) WAITVM(4);
    else                      WAITVM(0);
    __builtin_amdgcn_sched_barrier(0);
    __builtin_amdgcn_s_barrier();          // buf[cur] ready for all waves
    bf16x8 af[4], bfr[4];
#pragma unroll
    for (int mi = 0; mi < 4; ++mi)
      af[mi] = *(const bf16x8*)&As[cur][(wrow + mi * 16 + lr) * 32 + sw];
#pragma unroll
    for (int nj = 0; nj < 4; ++nj)
      bfr[nj] = *(const bf16x8*)&Bs[cur][(wcol + nj * 16 + lr) * 32 + sw];
    __builtin_amdgcn_s_setprio(1);
#pragma unroll
    for (int mi = 0; mi < 4; ++mi)
#pragma unroll
      for (int nj = 0; nj < 4; ++nj)
        acc[mi][nj] = __builtin_amdgcn_mfma_f32_16x16x32_bf16(af[mi], bfr[nj], acc[mi][nj], 0, 0, 0);
    __builtin_amdgcn_s_setprio(0);
    __builtin_amdgcn_s_barrier();          // all reads of buf[cur] done
    if (ks + 3 < KSTEPS) { GK_STAGE(ks + 3, cur) }   // refill freed buffer
    cur = (cur == 2) ? 0 : cur + 1;
  }
#undef GK_STAGE

  const size_t bD = (size_t)bb * sD;
  if (EPI == 3) {
#pragma unroll
    for (int mi = 0; mi < 4; ++mi) {
#pragma unroll
      for (int r = 0; r < 4; ++r) {
        const int row = row0 + wrow + mi * 16 + lg * 4 + r;
        const float bv = bias[row];
        s16x4 o = { f2bf(acc[mi][0][r] + bv), f2bf(acc[mi][1][r] + bv),
                    f2bf(acc[mi][2][r] + bv), f2bf(acc[mi][3][r] + bv) };
        *(s16x4*)&((short*)Dp)[bD + (size_t)row * N + col0 + wcol + lr * 4] = o;
      }
    }
  } else {
#pragma unroll
    for (int mi = 0; mi < 4; ++mi) {
#pragma unroll
      for (int nj = 0; nj < 4; ++nj) {
        const int col = col0 + wcol + nj * 16 + lr;
#pragma unroll
        for (int r = 0; r < 4; ++r) {
          const int row = row0 + wrow + mi * 16 + lg * 4 + r;
          float v = acc[mi][nj][r];
          if (EPI != 2) v += (BIASROW ? bias[row] : bias[col]);
          const size_t idx = bD + (size_t)row * N + col;
          if (EPI == 1) {
            ((float*)Dp)[idx] = v + resid[idx];
          } else {
            ((short*)Dp)[idx] = f2bf(v);
          }
        }
      }
    }
  }
}

// ---------------- S-GEMM, fixed-offset softmax epilogue ---------------------
// S[i][j] = z_i . y_j ; P = exp(S - 30) stored bf16, column-PERMUTED within
// 64-blocks (matches vbuf's n-permutation), packed 8B stores.
__global__ __launch_bounds__(256) void gemm_s(
    const short* __restrict__ z, const short* __restrict__ yT,
    short* __restrict__ Praw, float* __restrict__ Tsum, int b0) {
  __shared__ short As[3][128 * 32];
  __shared__ short Bs[3][128 * 32];
  const int cb = blockIdx.y;
  const int b = b0 + cb;
  int bx = blockIdx.x;                    // 324 tiles: bijective 8-way split (41/40)
  { const int xcd = bx & 7, id8 = bx >> 3;
    bx = (xcd < 4 ? xcd * 41 : 164 + (xcd - 4) * 40) + id8; }
  const int tm = bx % 18, tn = bx / 18;
  const int row0 = tm * 128, col0 = tn * 128;
  const int tid = threadIdx.x, lane = tid & 63, w = tid >> 6;
  const int lr = lane & 15, lg = lane >> 4;
  const short* Ab = z + (size_t)b * 2304 * 512;
  const short* Bb = yT + (size_t)b * 2304 * 512;
  f32x4 acc[4][4];
  const f32x4 zero = {0.f, 0.f, 0.f, 0.f};
#pragma unroll
  for (int i = 0; i < 4; ++i)
#pragma unroll
    for (int j = 0; j < 4; ++j) acc[i][j] = zero;
  const int wrow = (w & 1) * 64, wcol = (w >> 1) * 64;
  const int chalf = w >> 1;
  const int sw = (lg ^ ((lr >> 1) & 3)) * 8;

#define GS_STAGE(KS, BUF)                                                      \
  {                                                                            \
    _Pragma("unroll")                                                          \
    for (int j = 0; j < 2; ++j) {                                              \
      const int g = (w * 2 + j) * 64 + lane;                                   \
      const int ko = (KS) * 32 + (((g & 3) ^ ((g >> 3) & 3)) * 8);             \
      const short* ga = Ab + (size_t)(row0 + (g >> 2)) * 512 + ko;             \
      const short* gb = Bb + (size_t)(col0 + (g >> 2)) * 512 + ko;             \
      __builtin_amdgcn_global_load_lds(                                        \
          (__attribute__((address_space(1))) void*)ga,                         \
          (__attribute__((address_space(3))) void*)&As[BUF][(w * 2 + j) * 512],\
          16, 0, 0);                                                           \
      __builtin_amdgcn_global_load_lds(                                        \
          (__attribute__((address_space(1))) void*)gb,                         \
          (__attribute__((address_space(3))) void*)&Bs[BUF][(w * 2 + j) * 512],\
          16, 0, 0);                                                           \
    }                                                                          \
  }

  GS_STAGE(0, 0);
  GS_STAGE(1, 1);
  GS_STAGE(2, 2);
  int cur = 0;
  for (int ks = 0; ks < 16; ++ks) {
    if (ks < 14)      WAITVM(8);
    else if (ks < 15) WAITVM(4);
    else              WAITVM(0);
    __builtin_amdgcn_sched_barrier(0);
    __builtin_amdgcn_s_barrier();
    bf16x8 af[4], bfr[4];
#pragma unroll
    for (int mi = 0; mi < 4; ++mi)
      af[mi] = *(const bf16x8*)&As[cur][(wrow + mi * 16 + lr) * 32 + sw];
#pragma unroll
    for (int nj = 0; nj < 4; ++nj)
      bfr[nj] = *(const bf16x8*)&Bs[cur][(wcol + nj * 16 + lr) * 32 + sw];
    __builtin_amdgcn_s_setprio(1);
#pragma unroll
    for (int mi = 0; mi < 4; ++mi)
#pragma unroll
      for (int nj = 0; nj < 4; ++nj)
        acc[mi][nj] = __builtin_amdgcn_mfma_f32_16x16x32_bf16(af[mi], bfr[nj], acc[mi][nj], 0, 0, 0);
    __builtin_amdgcn_s_setprio(0);
    __builtin_amdgcn_s_barrier();
    if (ks + 3 < 16) { GS_STAGE(ks + 3, cur) }
    cur = (cur == 2) ? 0 : cur + 1;
  }
#undef GS_STAGE
  // epilogue: exp(acc-30), per-row partial sums, packed bf16 P store
  short* Pp = Praw + ((size_t)(cb * 18 + tn) * 2304 + row0) * 128;
  float* Ts = Tsum + (size_t)(cb * 2304 + row0) * 36 + tn * 2 + chalf;
#pragma unroll
  for (int mi = 0; mi < 4; ++mi) {
#pragma unroll
    for (int r = 0; r < 4; ++r) {
      const int row = wrow + mi * 16 + lg * 4 + r;
      float pv0 = __expf(acc[mi][0][r] - 30.f);
      float pv1 = __expf(acc[mi][1][r] - 30.f);
      float pv2 = __expf(acc[mi][2][r] - 30.f);
      float pv3 = __expf(acc[mi][3][r] - 30.f);
      float sum = pv0 + pv1 + pv2 + pv3;
#pragma unroll
      for (int d = 1; d < 16; d <<= 1) sum += __shfl_xor(sum, d);
      if (lr == 0) Ts[(size_t)row * 36] = sum;
      s16x4 o = { f2bf(pv0), f2bf(pv1), f2bf(pv2), f2bf(pv3) };
      *(s16x4*)(Pp + (size_t)row * 128 + wcol + lr * 4) = o;
    }
  }
}

// ---------------- linv[row] = 1 / sum_t Tsum[row][t] ------------------------
__global__ __launch_bounds__(256) void sum_k(
    const float* __restrict__ Tsum, float* __restrict__ linv, int nrows) {
  const int r = blockIdx.x * 256 + threadIdx.x;
  if (r >= nrows) return;
  const float* ts = Tsum + (size_t)r * 36;
  float l = 0.f;
#pragma unroll
  for (int t = 0; t < 36; ++t) l += ts[t];
  linv[r] = 1.f / l;
}

// ---------------- PV GEMM v4: 144x512 tile, BK=64, 36 syncs -----------------
// oT[i][c] = linv[i] * sum_j Praw[i][j] * v[c][j]  (j,c in permuted space)
// Grid 16x16 = 256 blocks = exactly 1 block/CU (R5's proven lever). BK 32->64
// halves the barrier-pair count (72 -> 36): per-sync overhead was ~4400 cy at
// only ~600 cy of issue work (R5: 23% MfmaUtil, no BW saturated). LDS layout
// per buffer is [half][144][32] so the ds_read keeps R5's conflict-free
// swizzle (a flat [144][64] would be a 4-way conflict). A-ring depth-3
// (3 x 18 KB); 18 slot-instructions/stage: waves 0-1 issue 3, waves 2-7
// issue 2 -> wave-dependent vmcnt literals (22/20 steady, 19/18, 8).
// V loads straight from L2 to regs, two 8-reg banks, filled 2 iters ahead.
__global__ __launch_bounds__(512) void gemm_pv(
    const short* __restrict__ Praw, const float* __restrict__ linv,
    const short* __restrict__ vsrc, short* __restrict__ Dp, int b0) {
  __shared__ short As[3][144 * 64];   // 3 x 18 KB
  int tm, cb;
  if (gridDim.y == 16) {
    const int id = blockIdx.y * 16 + blockIdx.x;   // 256 blocks
    const int xcd = id & 7, r = id >> 3;           // r in [0,32)
    cb = xcd * 2 + (r >= 16 ? 1 : 0);
    tm = r & 15;
  } else {
    cb = blockIdx.y; tm = blockIdx.x;
  }
  const int bb = b0 + cb;
  const int row0 = tm * 144;
  const int tid = threadIdx.x, lane = tid & 63, w = tid >> 6;  // 8 waves
  const int lr = lane & 15, lg = lane >> 4;
  const short* Ab = Praw + (size_t)cb * 18 * 2304 * 128;
  const short* Bb = vsrc + (size_t)bb * 512 * 2304;
  const short* Bp0 = Bb + (size_t)(w * 64 +  0 + lr) * 2304 + lg * 8;
  const short* Bp1 = Bb + (size_t)(w * 64 + 16 + lr) * 2304 + lg * 8;
  const short* Bp2 = Bb + (size_t)(w * 64 + 32 + lr) * 2304 + lg * 8;
  const short* Bp3 = Bb + (size_t)(w * 64 + 48 + lr) * 2304 + lg * 8;
  f32x4 acc[9][4];
  const f32x4 zero = {0.f, 0.f, 0.f, 0.f};
#pragma unroll
  for (int i = 0; i < 9; ++i)
#pragma unroll
    for (int j = 0; j < 4; ++j) acc[i][j] = zero;
  const int sw = (lg ^ ((lr >> 1) & 3)) * 8;

  // A stage (K-chunk of 64): 144x64 shorts = 1152 x 16B chunks = 18 slots of
  // 64 lanes. LDS chunk q -> [half=q/576][row=(q%576)>>2][sub=q&3]; global
  // source pre-swizzled sub' = sub ^ ((row>>1)&3).
#define PVA_SLOT(KS, BUF, S)                                                   \
  {                                                                            \
    const int q = (S) * 64 + lane;                                             \
    const int hf = (q >= 576) ? 1 : 0;                                         \
    const int row = (q - hf * 576) >> 2, sub = q & 3;                          \
    const short* ga = Ab + ((size_t)((KS) >> 1) * 2304 + row0 + row) * 128 +   \
                      ((KS) & 1) * 64 + hf * 32 +                              \
                      ((sub ^ ((row >> 1) & 3)) * 8);                          \
    __builtin_amdgcn_global_load_lds(                                          \
        (__attribute__((address_space(1))) void*)ga,                           \
        (__attribute__((address_space(3))) void*)&As[BUF][(S) * 512], 16,0,0); \
  }
#define PVA_STAGE(KS, BUF)                                                     \
  {                                                                            \
    PVA_SLOT(KS, BUF, w);                                                      \
    PVA_SLOT(KS, BUF, w + 8);                                                  \
    if (w < 2) PVA_SLOT(KS, BUF, w + 16);                                      \
  }

#define PV_BLOAD(KS, BR)                                                       \
  {                                                                            \
    BR[0] = *(const bf16x8*)(Bp0 + (KS) * 64);                                 \
    BR[1] = *(const bf16x8*)(Bp1 + (KS) * 64);                                 \
    BR[2] = *(const bf16x8*)(Bp2 + (KS) * 64);                                 \
    BR[3] = *(const bf16x8*)(Bp3 + (KS) * 64);                                 \
    BR[4] = *(const bf16x8*)(Bp0 + (KS) * 64 + 32);                            \
    BR[5] = *(const bf16x8*)(Bp1 + (KS) * 64 + 32);                            \
    BR[6] = *(const bf16x8*)(Bp2 + (KS) * 64 + 32);                            \
    BR[7] = *(const bf16x8*)(Bp3 + (KS) * 64 + 32);                            \
  }

  // Steady outstanding at iter top (oldest first), a = A-loads/stage (3 for
  // waves 0-1, 2 for 2-7): A(ks)a, B(ks)8, A(ks+1)a, B(ks+1)8, A(ks+2)a
  // -> WAITVM(2a+16) retires exactly A(ks). Compiler's own register waits
  // retire B(ks) (oldest 8 of the remainder) before first MFMA use.
#define PV_ITER(KS, BUSE, BFILL)                                               \
  {                                                                            \
    if ((KS) < 34)       { if (w < 2) WAITVM(22); else WAITVM(20); }           \
    else if ((KS) == 34) { if (w < 2) WAITVM(19); else WAITVM(18); }           \
    else                 WAITVM(8);                                            \
    __builtin_amdgcn_sched_barrier(0);                                         \
    __builtin_amdgcn_s_barrier();                                              \
    bf16x8 af[9];                                                              \
    _Pragma("unroll")                                                          \
    for (int mi = 0; mi < 9; ++mi)                                             \
      af[mi] = *(const bf16x8*)&As[cur][(mi * 16 + lr) * 32 + sw];             \
    __builtin_amdgcn_s_setprio(1);                                             \
    _Pragma("unroll")                                                          \
    for (int mi = 0; mi < 9; ++mi)                                             \
      _Pragma("unroll")                                                        \
      for (int nj = 0; nj < 4; ++nj)                                           \
        acc[mi][nj] = __builtin_amdgcn_mfma_f32_16x16x32_bf16(                 \
            af[mi], BUSE[nj], acc[mi][nj], 0, 0, 0);                           \
    __builtin_amdgcn_s_setprio(0);                                             \
    _Pragma("unroll")                                                          \
    for (int mi = 0; mi < 9; ++mi)                                             \
      af[mi] = *(const bf16x8*)&As[cur][4608 + (mi * 16 + lr) * 32 + sw];      \
    __builtin_amdgcn_s_setprio(1);                                             \
    _Pragma("unroll")                                                          \
    for (int mi = 0; mi < 9; ++mi)                                             \
      _Pragma("unroll")                                                        \
      for (int nj = 0; nj < 4; ++nj)                                           \
        acc[mi][nj] = __builtin_amdgcn_mfma_f32_16x16x32_bf16(                 \
            af[mi], BUSE[4 + nj], acc[mi][nj], 0, 0, 0);                       \
    __builtin_amdgcn_s_setprio(0);                                             \
    __builtin_amdgcn_s_barrier();                                              \
    if ((KS) + 2 < 36) PV_BLOAD((KS) + 2, BFILL);                              \
    if ((KS) + 3 < 36) PVA_STAGE((KS) + 3, cur);                               \
    cur = (cur == 2) ? 0 : cur + 1;                                            \
  }

  bf16x8 bA[8], bB[8];
  PVA_STAGE(0, 0);
  PVA_STAGE(1, 1);
  PVA_STAGE(2, 2);
  PV_BLOAD(0, bA);
  PV_BLOAD(1, bB);
  int cur = 0;
  for (int ks = 0; ks < 36; ks += 2) {
    PV_ITER(ks, bA, bA);
    PV_ITER(ks + 1, bB, bB);
  }
#undef PV_ITER
#undef PV_BLOAD
#undef PVA_STAGE
#undef PVA_SLOT

  const float* lv = linv + (size_t)cb * 2304 + row0;
  short* Db = Dp + (size_t)bb * 2304 * 512;
#pragma unroll
  for (int mi = 0; mi < 9; ++mi) {
#pragma unroll
    for (int r = 0; r < 4; ++r) {
      const int row = mi * 16 + lg * 4 + r;
      const float s = lv[row];
      s16x4 o = { f2bf(acc[mi][0][r] * s), f2bf(acc[mi][1][r] * s),
                  f2bf(acc[mi][2][r] * s), f2bf(acc[mi][3][r] * s) };
      // c-permuted within 64-block (matches Wo): position = w*64 + lr*4 + nj
      *(s16x4*)(Db + (size_t)(row0 + row) * 512 + w * 64 + lr * 4) = o;
    }
  }
}

// ---------------- launcher ---------------------------------------------------
extern "C" void kernel_launch(void* const* d_in, const int* in_sizes, int n_in,
                              void* d_out, int out_size, void* d_ws, size_t ws_size,
                              hipStream_t stream) {
  const float* x     = (const float*)d_in[0];
  const float* gamma = (const float*)d_in[1];
  const float* beta  = (const float*)d_in[2];
  const float* wq    = (const float*)d_in[3];
  const float* bq    = (const float*)d_in[4];
  const float* wk    = (const float*)d_in[5];
  // d_in[6] = bk: unused (per-row constant, cancels in softmax)
  const float* wv    = (const float*)d_in[7];
  const float* bv    = (const float*)d_in[8];
  const float* wo    = (const float*)d_in[9];
  const float* bo    = (const float*)d_in[10];

  char* ws = (char*)d_ws;
  float2* stats = (float2*)(ws + 0);
  short*  Wv    = (short*)(ws + 8192);
  short*  Wo    = (short*)(ws + 532480);
  short*  WkT   = (short*)(ws + 1056768);
  short*  WqT   = (short*)(ws + 1581056);
  short*  G     = (short*)(ws + 2105344);
  float*  g0    = (float*)(ws + 2629632);
  short*  yT    = (short*)(ws + 2631680);     //  36 MB  [B][2304][512]
  short*  zoT   = (short*)(ws + 40380416);    //  36 MB  z, overwritten by oT
  short*  vbuf  = (short*)(ws + 78129152);    //  36 MB  [B][512][2304] (n-permuted)
  short*  Praw  = (short*)(ws + 115877888);   //  CH * 10,616,832 [b][18][2304][128]
  float*  out   = (float*)d_out;

  const size_t base = 115877888ull;
  const size_t per  = 10616832ull + 331776ull + 9216ull;  // Praw+Tsum+linv
  int CH = 16;
  if (ws_size < base + 16 * per) CH = (ws_size >= base + 8 * per) ? 8 : 4;
  float* Tsum = (float*)(ws + base + (size_t)CH * 10616832ull);
  float* linv = (float*)(ws + base + (size_t)CH * (10616832ull + 331776ull));

  const size_t sBN = (size_t)2304 * 512;

  prep_k<<<1024, 256, 0, stream>>>(wq, wk, wv, wo, Wv, Wo, WkT, WqT);
  g0_k<<<2, 256, 0, stream>>>(wk, bq, g0);
  gn_stats<<<512, 256, 0, stream>>>(x, stats);
  gn_norm_t<<<dim3(36, 8, 16), 256, 0, stream>>>(x, stats, gamma, beta, yT);
  // G[c'][c] = sum_o WkT[c'][o] * WqT[c][o]
  gemm_k<2, false, 512, 512, 16><<<dim3(16, 1), 256, 0, stream>>>(
      WkT, 0, WqT, 0, G, 0, nullptr, nullptr, 512, 4, 0);
  // v[b][o][n] = sum_c Wv[o][c] * yT[b][n][c] + bv[o]  (n-permuted store)
  gemm_k<3, true, 512, 512, 16><<<dim3(72, 16), 256, 0, stream>>>(
      Wv, 0, yT, sBN, vbuf, sBN, bv, nullptr, 2304, 4, 0);
  // z[b][i][c'] = sum_c yT[b][i][c] * G[c'][c] + g0[c']
  gemm_k<0, false, 512, 512, 16><<<dim3(72, 16), 256, 0, stream>>>(
      yT, sBN, G, 0, zoT, sBN, g0, nullptr, 512, 18, 0);

  for (int b0 = 0; b0 < 16; b0 += CH) {
    const int n = (16 - b0 < CH) ? (16 - b0) : CH;
    gemm_s<<<dim3(324, n), 256, 0, stream>>>(zoT, yT, Praw, Tsum, b0);
    sum_k<<<(n * 2304 + 255) / 256, 256, 0, stream>>>(Tsum, linv, n * 2304);
    gemm_pv<<<dim3(16, n), 512, 0, stream>>>(Praw, linv, vbuf, zoT, b0);
  }
  // out[b][o][n] = sum_c Wo[o][c] * oT[b][n][c] + bo[o] + x[b][o][n]
  // (c-permutation on both Wo and oT cancels in the contraction)
  gemm_k<1, true, 512, 512, 16><<<dim3(72, 16), 256, 0, stream>>>(
      Wo, 0, zoT, sBN, out, (size_t)512 * 2304, bo, x, 2304, 4, 0);
}

// Round 7
// 567.926 us; speedup vs baseline: 1.2754x; 1.2754x over previous
//
#include <hip/hip_runtime.h>

#define DI __device__ __forceinline__

typedef __attribute__((ext_vector_type(8))) short bf16x8;
typedef __attribute__((ext_vector_type(4))) short s16x4;
typedef __attribute__((ext_vector_type(4))) float f32x4;

DI short f2bf(float f) {
  unsigned u = __builtin_bit_cast(unsigned, f);
  u += 0x7FFFu + ((u >> 16) & 1u);
  return (short)(u >> 16);
}

#define WAITVM(N) asm volatile("s_waitcnt vmcnt(" #N ")" ::: "memory")

// Within-64 column permutation used for packed epilogues:
//   position p holds true column c:  p = (c&~63) + (c&15)*4 + ((c>>4)&3)
// Applied consistently to {P cols, vbuf n} (PV contraction) and
// {Wo cols, oT cols} (output-GEMM contraction) -> cancels algebraically.

// ---------------- prep: weights -> bf16 (+ transposed Wk/Wq for G) ----------
__global__ __launch_bounds__(256) void prep_k(
    const float* __restrict__ wq, const float* __restrict__ wk,
    const float* __restrict__ wv, const float* __restrict__ wo,
    short* __restrict__ Wv, short* __restrict__ Wo,
    short* __restrict__ WkT, short* __restrict__ WqT) {
  const int i = blockIdx.x * 256 + threadIdx.x;  // 0..262143
  const float sc = 0.04419417382415922f;         // 1/sqrt(512)
  Wv[i] = f2bf(wv[i]);
  const int c = i & 511;
  const int cp = (c & ~63) | ((c & 15) << 2) | ((c >> 4) & 3);
  Wo[(i & ~511) | cp] = f2bf(wo[i]);             // c-permuted to match oT
  const int tr = (i & 511) * 512 + (i >> 9);
  WkT[tr] = f2bf(wk[i] * sc);   // scale folded into Wk side
  WqT[tr] = f2bf(wq[i]);
}

// ---------------- g0[c'] = s * sum_o wk[o][c'] * bq[o] ----------------------
__global__ __launch_bounds__(256) void g0_k(const float* __restrict__ wk,
                                            const float* __restrict__ bq,
                                            float* __restrict__ g0) {
  const int c = blockIdx.x * 256 + threadIdx.x;  // 0..511
  float acc = 0.f;
#pragma unroll 8
  for (int o = 0; o < 512; ++o) acc += wk[o * 512 + c] * bq[o];
  g0[c] = acc * 0.04419417382415922f;
}

// ---------------- GroupNorm pass 1: per (b,g) mean/rstd ---------------------
__global__ __launch_bounds__(256) void gn_stats(const float* __restrict__ x,
                                                float2* __restrict__ stats) {
  const int bg = blockIdx.x;
  const float4* xg = (const float4*)(x + (size_t)bg * 36864);
  float s = 0.f, q = 0.f;
  for (int i = threadIdx.x; i < 9216; i += 256) {
    float4 v = xg[i];
    s += v.x + v.y + v.z + v.w;
    q += v.x * v.x + v.y * v.y + v.z * v.z + v.w * v.w;
  }
#pragma unroll
  for (int d = 1; d < 64; d <<= 1) { s += __shfl_xor(s, d); q += __shfl_xor(q, d); }
  __shared__ float rs[4], rq[4];
  const int w = threadIdx.x >> 6;
  if ((threadIdx.x & 63) == 0) { rs[w] = s; rq[w] = q; }
  __syncthreads();
  if (threadIdx.x == 0) {
    float S = rs[0] + rs[1] + rs[2] + rs[3];
    float Q = rq[0] + rq[1] + rq[2] + rq[3];
    float mean = S * (1.f / 36864.f);
    float var  = Q * (1.f / 36864.f) - mean * mean;
    float2 o; o.x = mean; o.y = rsqrtf(var + 1e-5f);
    stats[bg] = o;
  }
}

// ---------------- GroupNorm pass 2: normalize + transpose -> yT bf16 --------
__global__ __launch_bounds__(256) void gn_norm_t(
    const float* __restrict__ x, const float2* __restrict__ stats,
    const float* __restrict__ gamma, const float* __restrict__ beta,
    short* __restrict__ yT) {
  __shared__ float ts[64][68];
  const int n0 = blockIdx.x * 64, c0 = blockIdx.y * 64, b = blockIdx.z;
  const int t = threadIdx.x;
  {
    const int cw = t >> 4;
    const int n4 = (t & 15) * 4;
    const float* xb = x + ((size_t)b * 512 + c0) * 2304 + n0;
#pragma unroll
    for (int r4 = 0; r4 < 4; ++r4) {
      const int c = cw + r4 * 16;
      float4 v = *(const float4*)(xb + (size_t)c * 2304 + n4);
      *(float4*)&ts[c][n4] = v;
    }
  }
  __syncthreads();
  {
    const int c4 = t & 15;
    const int nw = t >> 4;
    const int cg = c0 + c4 * 4;
    const float2 ms = stats[b * 32 + (cg >> 4)];
    const float4 gm = *(const float4*)(gamma + cg);
    const float4 bt = *(const float4*)(beta + cg);
    const float a0 = ms.y * gm.x, a1 = ms.y * gm.y, a2 = ms.y * gm.z, a3 = ms.y * gm.w;
    const float d0 = bt.x - ms.x * a0, d1 = bt.y - ms.x * a1,
                d2 = bt.z - ms.x * a2, d3 = bt.w - ms.x * a3;
#pragma unroll
    for (int it = 0; it < 4; ++it) {
      const int no = nw + it * 16;
      const float v0 = ts[c4 * 4 + 0][no], v1 = ts[c4 * 4 + 1][no];
      const float v2 = ts[c4 * 4 + 2][no], v3 = ts[c4 * 4 + 3][no];
      s16x4 o = { f2bf(v0 * a0 + d0), f2bf(v1 * a1 + d1),
                  f2bf(v2 * a2 + d2), f2bf(v3 * a3 + d3) };
      *(s16x4*)(yT + ((size_t)b * 2304 + n0 + no) * 512 + cg) = o;
    }
  }
}

// ---------------- Generic bf16 MFMA GEMM (depth-3 ring) ---------------------
// D[M][N] = A[M][K] * Bt[N][K]^T, 128x128 tile, BK=32.
template <int EPI, bool BIASROW, int LDA, int LDB, int KSTEPS>
__global__ __launch_bounds__(256) void gemm_k(
    const short* __restrict__ A, size_t sA,
    const short* __restrict__ Bt, size_t sB,
    void* __restrict__ Dp, size_t sD,
    const float* __restrict__ bias, const float* __restrict__ resid,
    int N, int tilesM, int boff) {
  __shared__ short As[3][128 * 32];
  __shared__ short Bs[3][128 * 32];
  const int ba = blockIdx.y, bb = blockIdx.y + boff;
  int bx = blockIdx.x;
  bx = (bx & 7) * (int)(gridDim.x >> 3) + (bx >> 3);  // XCD-contiguous; grid.x % 8 == 0
  const int tm = bx % tilesM, tn = bx / tilesM;
  const int row0 = tm * 128, col0 = tn * 128;
  const int tid = threadIdx.x, lane = tid & 63, w = tid >> 6;
  const int lr = lane & 15, lg = lane >> 4;
  const short* Ab = A + (size_t)ba * sA;
  const short* Bb = Bt + (size_t)bb * sB;
  f32x4 acc[4][4];
  const f32x4 zero = {0.f, 0.f, 0.f, 0.f};
#pragma unroll
  for (int i = 0; i < 4; ++i)
#pragma unroll
    for (int j = 0; j < 4; ++j) acc[i][j] = zero;
  const int wrow = (w & 1) * 64, wcol = (w >> 1) * 64;
  const int sw = (lg ^ ((lr >> 1) & 3)) * 8;  // swizzled K-chunk (shorts)

#define GK_STAGE(KS, BUF)                                                      \
  {                                                                            \
    _Pragma("unroll")                                                          \
    for (int j = 0; j < 2; ++j) {                                              \
      const int g = (w * 2 + j) * 64 + lane; /* 16B chunks 0..511 */           \
      const int ko = (KS) * 32 + (((g & 3) ^ ((g >> 3) & 3)) * 8);             \
      const short* ga = Ab + (size_t)(row0 + (g >> 2)) * LDA + ko;             \
      const short* gb = Bb + (size_t)(col0 + (g >> 2)) * LDB + ko;             \
      __builtin_amdgcn_global_load_lds(                                        \
          (__attribute__((address_space(1))) void*)ga,                         \
          (__attribute__((address_space(3))) void*)&As[BUF][(w * 2 + j) * 512],\
          16, 0, 0);                                                           \
      __builtin_amdgcn_global_load_lds(                                        \
          (__attribute__((address_space(1))) void*)gb,                         \
          (__attribute__((address_space(3))) void*)&Bs[BUF][(w * 2 + j) * 512],\
          16, 0, 0);                                                           \
    }                                                                          \
  }

  GK_STAGE(0, 0);
  GK_STAGE(1, 1);
  GK_STAGE(2, 2);
  int cur = 0;
  for (int ks = 0; ks < KSTEPS; ++ks) {
    if (ks + 2 < KSTEPS)      WAITVM(8);   // 3 stages out: oldest landed
    else if (ks + 1 < KSTEPS) WAITVM(4);
    else                      WAITVM(0);
    __builtin_amdgcn_sched_barrier(0);
    __builtin_amdgcn_s_barrier();          // buf[cur] ready for all waves
    bf16x8 af[4], bfr[4];
#pragma unroll
    for (int mi = 0; mi < 4; ++mi)
      af[mi] = *(const bf16x8*)&As[cur][(wrow + mi * 16 + lr) * 32 + sw];
#pragma unroll
    for (int nj = 0; nj < 4; ++nj)
      bfr[nj] = *(const bf16x8*)&Bs[cur][(wcol + nj * 16 + lr) * 32 + sw];
    __builtin_amdgcn_s_setprio(1);
#pragma unroll
    for (int mi = 0; mi < 4; ++mi)
#pragma unroll
      for (int nj = 0; nj < 4; ++nj)
        acc[mi][nj] = __builtin_amdgcn_mfma_f32_16x16x32_bf16(af[mi], bfr[nj], acc[mi][nj], 0, 0, 0);
    __builtin_amdgcn_s_setprio(0);
    __builtin_amdgcn_s_barrier();          // all reads of buf[cur] done
    if (ks + 3 < KSTEPS) { GK_STAGE(ks + 3, cur) }   // refill freed buffer
    cur = (cur == 2) ? 0 : cur + 1;
  }
#undef GK_STAGE

  const size_t bD = (size_t)bb * sD;
  if (EPI == 3) {
#pragma unroll
    for (int mi = 0; mi < 4; ++mi) {
#pragma unroll
      for (int r = 0; r < 4; ++r) {
        const int row = row0 + wrow + mi * 16 + lg * 4 + r;
        const float bv = bias[row];
        s16x4 o = { f2bf(acc[mi][0][r] + bv), f2bf(acc[mi][1][r] + bv),
                    f2bf(acc[mi][2][r] + bv), f2bf(acc[mi][3][r] + bv) };
        *(s16x4*)&((short*)Dp)[bD + (size_t)row * N + col0 + wcol + lr * 4] = o;
      }
    }
  } else {
#pragma unroll
    for (int mi = 0; mi < 4; ++mi) {
#pragma unroll
      for (int nj = 0; nj < 4; ++nj) {
        const int col = col0 + wcol + nj * 16 + lr;
#pragma unroll
        for (int r = 0; r < 4; ++r) {
          const int row = row0 + wrow + mi * 16 + lg * 4 + r;
          float v = acc[mi][nj][r];
          if (EPI != 2) v += (BIASROW ? bias[row] : bias[col]);
          const size_t idx = bD + (size_t)row * N + col;
          if (EPI == 1) {
            ((float*)Dp)[idx] = v + resid[idx];
          } else {
            ((short*)Dp)[idx] = f2bf(v);
          }
        }
      }
    }
  }
}

// ---------------- S-GEMM, fixed-offset softmax epilogue ---------------------
// S[i][j] = z_i . y_j ; P = exp(S - 30) stored bf16, column-PERMUTED within
// 64-blocks (matches vbuf's n-permutation), packed 8B stores.
__global__ __launch_bounds__(256) void gemm_s(
    const short* __restrict__ z, const short* __restrict__ yT,
    short* __restrict__ Praw, float* __restrict__ Tsum, int b0) {
  __shared__ short As[3][128 * 32];
  __shared__ short Bs[3][128 * 32];
  const int cb = blockIdx.y;
  const int b = b0 + cb;
  int bx = blockIdx.x;                    // 324 tiles: bijective 8-way split (41/40)
  { const int xcd = bx & 7, id8 = bx >> 3;
    bx = (xcd < 4 ? xcd * 41 : 164 + (xcd - 4) * 40) + id8; }
  const int tm = bx % 18, tn = bx / 18;
  const int row0 = tm * 128, col0 = tn * 128;
  const int tid = threadIdx.x, lane = tid & 63, w = tid >> 6;
  const int lr = lane & 15, lg = lane >> 4;
  const short* Ab = z + (size_t)b * 2304 * 512;
  const short* Bb = yT + (size_t)b * 2304 * 512;
  f32x4 acc[4][4];
  const f32x4 zero = {0.f, 0.f, 0.f, 0.f};
#pragma unroll
  for (int i = 0; i < 4; ++i)
#pragma unroll
    for (int j = 0; j < 4; ++j) acc[i][j] = zero;
  const int wrow = (w & 1) * 64, wcol = (w >> 1) * 64;
  const int chalf = w >> 1;
  const int sw = (lg ^ ((lr >> 1) & 3)) * 8;

#define GS_STAGE(KS, BUF)                                                      \
  {                                                                            \
    _Pragma("unroll")                                                          \
    for (int j = 0; j < 2; ++j) {                                              \
      const int g = (w * 2 + j) * 64 + lane;                                   \
      const int ko = (KS) * 32 + (((g & 3) ^ ((g >> 3) & 3)) * 8);             \
      const short* ga = Ab + (size_t)(row0 + (g >> 2)) * 512 + ko;             \
      const short* gb = Bb + (size_t)(col0 + (g >> 2)) * 512 + ko;             \
      __builtin_amdgcn_global_load_lds(                                        \
          (__attribute__((address_space(1))) void*)ga,                         \
          (__attribute__((address_space(3))) void*)&As[BUF][(w * 2 + j) * 512],\
          16, 0, 0);                                                           \
      __builtin_amdgcn_global_load_lds(                                        \
          (__attribute__((address_space(1))) void*)gb,                         \
          (__attribute__((address_space(3))) void*)&Bs[BUF][(w * 2 + j) * 512],\
          16, 0, 0);                                                           \
    }                                                                          \
  }

  GS_STAGE(0, 0);
  GS_STAGE(1, 1);
  GS_STAGE(2, 2);
  int cur = 0;
  for (int ks = 0; ks < 16; ++ks) {
    if (ks < 14)      WAITVM(8);
    else if (ks < 15) WAITVM(4);
    else              WAITVM(0);
    __builtin_amdgcn_sched_barrier(0);
    __builtin_amdgcn_s_barrier();
    bf16x8 af[4], bfr[4];
#pragma unroll
    for (int mi = 0; mi < 4; ++mi)
      af[mi] = *(const bf16x8*)&As[cur][(wrow + mi * 16 + lr) * 32 + sw];
#pragma unroll
    for (int nj = 0; nj < 4; ++nj)
      bfr[nj] = *(const bf16x8*)&Bs[cur][(wcol + nj * 16 + lr) * 32 + sw];
    __builtin_amdgcn_s_setprio(1);
#pragma unroll
    for (int mi = 0; mi < 4; ++mi)
#pragma unroll
      for (int nj = 0; nj < 4; ++nj)
        acc[mi][nj] = __builtin_amdgcn_mfma_f32_16x16x32_bf16(af[mi], bfr[nj], acc[mi][nj], 0, 0, 0);
    __builtin_amdgcn_s_setprio(0);
    __builtin_amdgcn_s_barrier();
    if (ks + 3 < 16) { GS_STAGE(ks + 3, cur) }
    cur = (cur == 2) ? 0 : cur + 1;
  }
#undef GS_STAGE
  // epilogue: exp(acc-30), per-row partial sums, packed bf16 P store
  short* Pp = Praw + ((size_t)(cb * 18 + tn) * 2304 + row0) * 128;
  float* Ts = Tsum + (size_t)(cb * 2304 + row0) * 36 + tn * 2 + chalf;
#pragma unroll
  for (int mi = 0; mi < 4; ++mi) {
#pragma unroll
    for (int r = 0; r < 4; ++r) {
      const int row = wrow + mi * 16 + lg * 4 + r;
      float pv0 = __expf(acc[mi][0][r] - 30.f);
      float pv1 = __expf(acc[mi][1][r] - 30.f);
      float pv2 = __expf(acc[mi][2][r] - 30.f);
      float pv3 = __expf(acc[mi][3][r] - 30.f);
      float sum = pv0 + pv1 + pv2 + pv3;
#pragma unroll
      for (int d = 1; d < 16; d <<= 1) sum += __shfl_xor(sum, d);
      if (lr == 0) Ts[(size_t)row * 36] = sum;
      s16x4 o = { f2bf(pv0), f2bf(pv1), f2bf(pv2), f2bf(pv3) };
      *(s16x4*)(Pp + (size_t)row * 128 + wcol + lr * 4) = o;
    }
  }
}

// ---------------- linv[row] = 1 / sum_t Tsum[row][t] ------------------------
__global__ __launch_bounds__(256) void sum_k(
    const float* __restrict__ Tsum, float* __restrict__ linv, int nrows) {
  const int r = blockIdx.x * 256 + threadIdx.x;
  if (r >= nrows) return;
  const float* ts = Tsum + (size_t)r * 36;
  float l = 0.f;
#pragma unroll
  for (int t = 0; t < 36; ++t) l += ts[t];
  linv[r] = 1.f / l;
}

// ---------------- PV GEMM v5: 48x256 tiles, 4 waves, 1536 blocks ------------
// oT[i][c] = linv[i] * sum_j Praw[i][j] * v[c][j]  (j,c in permuted space)
// R6 spilled (acc144+banks64 -> scratch, WRITE_SIZE 650MB). v5 goes the other
// way: SMALL independent blocks like gemm_s's proven structure. 48 rows x
// 256 cols, 4 waves (wave w owns c-slice 64; acc 3x4 f32x4 = 48 VGPR, ~120
// total -> no spill), LDS 9KB -> 3-4 blocks/CU RESIDENT with independent
// barriers (stall-filling TLP, m114). Grid 96x16 = 1536 = 6/CU exactly.
// Praw read twice (tn halves) — accepted for 4x TLP. Ring/swizzle/vmcnt
// discipline identical to R5; literals recomputed (10/8 steady by wave).
__global__ __launch_bounds__(256, 3) void gemm_pv(
    const short* __restrict__ Praw, const float* __restrict__ linv,
    const short* __restrict__ vsrc, short* __restrict__ Dp, int b0) {
  __shared__ short As[3][48 * 32];   // 3 x 3 KB
  int tm, tn, cb;
  if (gridDim.y == 16) {
    const int id = blockIdx.y * 96 + blockIdx.x;   // 1536 blocks
    const int xcd = id & 7, r = id >> 3;           // r in [0,192)
    cb = xcd * 2 + (r >= 96 ? 1 : 0);              // 2 batches per XCD
    const int rr = (r >= 96) ? r - 96 : r;         // [0,96)
    tn = rr / 48; tm = rr % 48;                    // tm fastest: share V slice
  } else {
    cb = blockIdx.y; tm = blockIdx.x >> 1; tn = blockIdx.x & 1;
  }
  const int bb = b0 + cb;
  const int row0 = tm * 48, c0 = tn * 256;
  const int tid = threadIdx.x, lane = tid & 63, w = tid >> 6;  // 4 waves
  const int lr = lane & 15, lg = lane >> 4;
  const short* Ab = Praw + (size_t)cb * 18 * 2304 * 128;
  const short* Bb = vsrc + (size_t)bb * 512 * 2304;
  const short* Bp0 = Bb + (size_t)(c0 + w * 64 +  0 + lr) * 2304 + lg * 8;
  const short* Bp1 = Bb + (size_t)(c0 + w * 64 + 16 + lr) * 2304 + lg * 8;
  const short* Bp2 = Bb + (size_t)(c0 + w * 64 + 32 + lr) * 2304 + lg * 8;
  const short* Bp3 = Bb + (size_t)(c0 + w * 64 + 48 + lr) * 2304 + lg * 8;
  f32x4 acc[3][4];
  const f32x4 zero = {0.f, 0.f, 0.f, 0.f};
#pragma unroll
  for (int i = 0; i < 3; ++i)
#pragma unroll
    for (int j = 0; j < 4; ++j) acc[i][j] = zero;
  const int sw = (lg ^ ((lr >> 1) & 3)) * 8;

  // A stage: 48x32 tile = 192 x 16B chunks; threads of waves 0-2 stage one
  // chunk each (wave 3 stages none -> wave-dependent vmcnt literals).
#define PVA_STAGE(KS, BUF)                                                     \
  if (w < 3) {                                                                 \
    const int kt = (KS) >> 2, k32 = ((KS) & 3) * 32;                           \
    const int g = tid; /* 0..191 */                                            \
    const short* ga = Ab + ((size_t)kt * 2304 + row0 + (g >> 2)) * 128 +       \
                      k32 + (((g & 3) ^ ((g >> 3) & 3)) * 8);                  \
    __builtin_amdgcn_global_load_lds(                                          \
        (__attribute__((address_space(1))) void*)ga,                           \
        (__attribute__((address_space(3))) void*)&As[BUF][w * 512], 16, 0, 0); \
  }

#define PV_BLOAD(KS, BR)                                                       \
  {                                                                            \
    BR[0] = *(const bf16x8*)(Bp0 + (KS) * 32);                                 \
    BR[1] = *(const bf16x8*)(Bp1 + (KS) * 32);                                 \
    BR[2] = *(const bf16x8*)(Bp2 + (KS) * 32);                                 \
    BR[3] = *(const bf16x8*)(Bp3 + (KS) * 32);                                 \
  }

  // Steady outstanding at iter top (oldest first), a = A-loads (1 for w<3,
  // 0 for w3): A(ks)a, B(ks)4, A(ks+1)a, B(ks+1)4, A(ks+2)a -> wait 8+2a
  // retires exactly A(ks). Compiler's register waits retire B(ks).
#define PV_ITER(KS, BUSE, BFILL)                                               \
  {                                                                            \
    if ((KS) < 70)       { if (w < 3) WAITVM(10); else WAITVM(8); }            \
    else if ((KS) == 70) { if (w < 3) WAITVM(9);  else WAITVM(8); }            \
    else                 WAITVM(4);                                            \
    __builtin_amdgcn_sched_barrier(0);                                         \
    __builtin_amdgcn_s_barrier();                                              \
    bf16x8 af[3];                                                              \
    _Pragma("unroll")                                                          \
    for (int mi = 0; mi < 3; ++mi)                                             \
      af[mi] = *(const bf16x8*)&As[cur][(mi * 16 + lr) * 32 + sw];             \
    __builtin_amdgcn_s_setprio(1);                                             \
    _Pragma("unroll")                                                          \
    for (int mi = 0; mi < 3; ++mi)                                             \
      _Pragma("unroll")                                                        \
      for (int nj = 0; nj < 4; ++nj)                                           \
        acc[mi][nj] = __builtin_amdgcn_mfma_f32_16x16x32_bf16(                 \
            af[mi], BUSE[nj], acc[mi][nj], 0, 0, 0);                           \
    __builtin_amdgcn_s_setprio(0);                                             \
    __builtin_amdgcn_s_barrier();                                              \
    if ((KS) + 2 < 72) PV_BLOAD((KS) + 2, BFILL);                              \
    if ((KS) + 3 < 72) PVA_STAGE((KS) + 3, cur);                               \
    cur = (cur == 2) ? 0 : cur + 1;                                            \
  }

  bf16x8 bA[4], bB[4];
  PVA_STAGE(0, 0);
  PVA_STAGE(1, 1);
  PVA_STAGE(2, 2);
  PV_BLOAD(0, bA);
  PV_BLOAD(1, bB);
  int cur = 0;
  for (int ks = 0; ks < 72; ks += 2) {
    PV_ITER(ks, bA, bA);
    PV_ITER(ks + 1, bB, bB);
  }
#undef PV_ITER
#undef PV_BLOAD
#undef PVA_STAGE

  const float* lv = linv + (size_t)cb * 2304 + row0;
  short* Db = Dp + (size_t)bb * 2304 * 512;
#pragma unroll
  for (int mi = 0; mi < 3; ++mi) {
#pragma unroll
    for (int r = 0; r < 4; ++r) {
      const int row = mi * 16 + lg * 4 + r;
      const float s = lv[row];
      s16x4 o = { f2bf(acc[mi][0][r] * s), f2bf(acc[mi][1][r] * s),
                  f2bf(acc[mi][2][r] * s), f2bf(acc[mi][3][r] * s) };
      // c-permuted within 64-block (matches Wo): position = c0+w*64+lr*4+nj
      *(s16x4*)(Db + (size_t)(row0 + row) * 512 + c0 + w * 64 + lr * 4) = o;
    }
  }
}

// ---------------- launcher ---------------------------------------------------
extern "C" void kernel_launch(void* const* d_in, const int* in_sizes, int n_in,
                              void* d_out, int out_size, void* d_ws, size_t ws_size,
                              hipStream_t stream) {
  const float* x     = (const float*)d_in[0];
  const float* gamma = (const float*)d_in[1];
  const float* beta  = (const float*)d_in[2];
  const float* wq    = (const float*)d_in[3];
  const float* bq    = (const float*)d_in[4];
  const float* wk    = (const float*)d_in[5];
  // d_in[6] = bk: unused (per-row constant, cancels in softmax)
  const float* wv    = (const float*)d_in[7];
  const float* bv    = (const float*)d_in[8];
  const float* wo    = (const float*)d_in[9];
  const float* bo    = (const float*)d_in[10];

  char* ws = (char*)d_ws;
  float2* stats = (float2*)(ws + 0);
  short*  Wv    = (short*)(ws + 8192);
  short*  Wo    = (short*)(ws + 532480);
  short*  WkT   = (short*)(ws + 1056768);
  short*  WqT   = (short*)(ws + 1581056);
  short*  G     = (short*)(ws + 2105344);
  float*  g0    = (float*)(ws + 2629632);
  short*  yT    = (short*)(ws + 2631680);     //  36 MB  [B][2304][512]
  short*  zoT   = (short*)(ws + 40380416);    //  36 MB  z, overwritten by oT
  short*  vbuf  = (short*)(ws + 78129152);    //  36 MB  [B][512][2304] (n-permuted)
  short*  Praw  = (short*)(ws + 115877888);   //  CH * 10,616,832 [b][18][2304][128]
  float*  out   = (float*)d_out;

  const size_t base = 115877888ull;
  const size_t per  = 10616832ull + 331776ull + 9216ull;  // Praw+Tsum+linv
  int CH = 16;
  if (ws_size < base + 16 * per) CH = (ws_size >= base + 8 * per) ? 8 : 4;
  float* Tsum = (float*)(ws + base + (size_t)CH * 10616832ull);
  float* linv = (float*)(ws + base + (size_t)CH * (10616832ull + 331776ull));

  const size_t sBN = (size_t)2304 * 512;

  prep_k<<<1024, 256, 0, stream>>>(wq, wk, wv, wo, Wv, Wo, WkT, WqT);
  g0_k<<<2, 256, 0, stream>>>(wk, bq, g0);
  gn_stats<<<512, 256, 0, stream>>>(x, stats);
  gn_norm_t<<<dim3(36, 8, 16), 256, 0, stream>>>(x, stats, gamma, beta, yT);
  // G[c'][c] = sum_o WkT[c'][o] * WqT[c][o]
  gemm_k<2, false, 512, 512, 16><<<dim3(16, 1), 256, 0, stream>>>(
      WkT, 0, WqT, 0, G, 0, nullptr, nullptr, 512, 4, 0);
  // v[b][o][n] = sum_c Wv[o][c] * yT[b][n][c] + bv[o]  (n-permuted store)
  gemm_k<3, true, 512, 512, 16><<<dim3(72, 16), 256, 0, stream>>>(
      Wv, 0, yT, sBN, vbuf, sBN, bv, nullptr, 2304, 4, 0);
  // z[b][i][c'] = sum_c yT[b][i][c] * G[c'][c] + g0[c']
  gemm_k<0, false, 512, 512, 16><<<dim3(72, 16), 256, 0, stream>>>(
      yT, sBN, G, 0, zoT, sBN, g0, nullptr, 512, 18, 0);

  for (int b0 = 0; b0 < 16; b0 += CH) {
    const int n = (16 - b0 < CH) ? (16 - b0) : CH;
    gemm_s<<<dim3(324, n), 256, 0, stream>>>(zoT, yT, Praw, Tsum, b0);
    sum_k<<<(n * 2304 + 255) / 256, 256, 0, stream>>>(Tsum, linv, n * 2304);
    gemm_pv<<<dim3(96, n), 256, 0, stream>>>(Praw, linv, vbuf, zoT, b0);
  }
  // out[b][o][n] = sum_c Wo[o][c] * oT[b][n][c] + bo[o] + x[b][o][n]
  // (c-permutation on both Wo and oT cancels in the contraction)
  gemm_k<1, true, 512, 512, 16><<<dim3(72, 16), 256, 0, stream>>>(
      Wo, 0, zoT, sBN, out, (size_t)512 * 2304, bo, x, 2304, 4, 0);
}

// Round 8
// 441.821 us; speedup vs baseline: 1.6394x; 1.2854x over previous
//
#include <hip/hip_runtime.h>

#define DI __device__ __forceinline__

typedef __attribute__((ext_vector_type(8))) short bf16x8;
typedef __attribute__((ext_vector_type(4))) short s16x4;
typedef __attribute__((ext_vector_type(4))) float f32x4;

DI short f2bf(float f) {
  unsigned u = __builtin_bit_cast(unsigned, f);
  u += 0x7FFFu + ((u >> 16) & 1u);
  return (short)(u >> 16);
}

#define WAITVM(N) asm volatile("s_waitcnt vmcnt(" #N ")" ::: "memory")

// Within-64 column permutation used for packed epilogues:
//   position p holds true column c:  p = (c&~63) + (c&15)*4 + ((c>>4)&3)
// Applied consistently to {P cols, vbuf j} (PV contraction) and
// {Wo cols, oT cols} (output-GEMM contraction) -> cancels algebraically.
//
// NEW (R8): vbuf physical layout is tiled per batch as [jb=72][cb=32][16][32]
//   off(c, j) = ((j>>5)*32 + (c>>4))*512 + (c&15)*32 + (j&31)
// so PV's B-load instructions read 1024 B fully contiguous (channel-spread),
// replacing the 4608B-row-stride scatter that camped on L2 channels.

// ---------------- prep: weights -> bf16 (+ transposed Wk/Wq for G) ----------
__global__ __launch_bounds__(256) void prep_k(
    const float* __restrict__ wq, const float* __restrict__ wk,
    const float* __restrict__ wv, const float* __restrict__ wo,
    short* __restrict__ Wv, short* __restrict__ Wo,
    short* __restrict__ WkT, short* __restrict__ WqT) {
  const int i = blockIdx.x * 256 + threadIdx.x;  // 0..262143
  const float sc = 0.04419417382415922f;         // 1/sqrt(512)
  Wv[i] = f2bf(wv[i]);
  const int c = i & 511;
  const int cp = (c & ~63) | ((c & 15) << 2) | ((c >> 4) & 3);
  Wo[(i & ~511) | cp] = f2bf(wo[i]);             // c-permuted to match oT
  const int tr = (i & 511) * 512 + (i >> 9);
  WkT[tr] = f2bf(wk[i] * sc);   // scale folded into Wk side
  WqT[tr] = f2bf(wq[i]);
}

// ---------------- g0[c'] = s * sum_o wk[o][c'] * bq[o] ----------------------
__global__ __launch_bounds__(256) void g0_k(const float* __restrict__ wk,
                                            const float* __restrict__ bq,
                                            float* __restrict__ g0) {
  const int c = blockIdx.x * 256 + threadIdx.x;  // 0..511
  float acc = 0.f;
#pragma unroll 8
  for (int o = 0; o < 512; ++o) acc += wk[o * 512 + c] * bq[o];
  g0[c] = acc * 0.04419417382415922f;
}

// ---------------- GroupNorm pass 1: per (b,g) mean/rstd ---------------------
__global__ __launch_bounds__(256) void gn_stats(const float* __restrict__ x,
                                                float2* __restrict__ stats) {
  const int bg = blockIdx.x;
  const float4* xg = (const float4*)(x + (size_t)bg * 36864);
  float s = 0.f, q = 0.f;
  for (int i = threadIdx.x; i < 9216; i += 256) {
    float4 v = xg[i];
    s += v.x + v.y + v.z + v.w;
    q += v.x * v.x + v.y * v.y + v.z * v.z + v.w * v.w;
  }
#pragma unroll
  for (int d = 1; d < 64; d <<= 1) { s += __shfl_xor(s, d); q += __shfl_xor(q, d); }
  __shared__ float rs[4], rq[4];
  const int w = threadIdx.x >> 6;
  if ((threadIdx.x & 63) == 0) { rs[w] = s; rq[w] = q; }
  __syncthreads();
  if (threadIdx.x == 0) {
    float S = rs[0] + rs[1] + rs[2] + rs[3];
    float Q = rq[0] + rq[1] + rq[2] + rq[3];
    float mean = S * (1.f / 36864.f);
    float var  = Q * (1.f / 36864.f) - mean * mean;
    float2 o; o.x = mean; o.y = rsqrtf(var + 1e-5f);
    stats[bg] = o;
  }
}

// ---------------- GroupNorm pass 2: normalize + transpose -> yT bf16 --------
__global__ __launch_bounds__(256) void gn_norm_t(
    const float* __restrict__ x, const float2* __restrict__ stats,
    const float* __restrict__ gamma, const float* __restrict__ beta,
    short* __restrict__ yT) {
  __shared__ float ts[64][68];
  const int n0 = blockIdx.x * 64, c0 = blockIdx.y * 64, b = blockIdx.z;
  const int t = threadIdx.x;
  {
    const int cw = t >> 4;
    const int n4 = (t & 15) * 4;
    const float* xb = x + ((size_t)b * 512 + c0) * 2304 + n0;
#pragma unroll
    for (int r4 = 0; r4 < 4; ++r4) {
      const int c = cw + r4 * 16;
      float4 v = *(const float4*)(xb + (size_t)c * 2304 + n4);
      *(float4*)&ts[c][n4] = v;
    }
  }
  __syncthreads();
  {
    const int c4 = t & 15;
    const int nw = t >> 4;
    const int cg = c0 + c4 * 4;
    const float2 ms = stats[b * 32 + (cg >> 4)];
    const float4 gm = *(const float4*)(gamma + cg);
    const float4 bt = *(const float4*)(beta + cg);
    const float a0 = ms.y * gm.x, a1 = ms.y * gm.y, a2 = ms.y * gm.z, a3 = ms.y * gm.w;
    const float d0 = bt.x - ms.x * a0, d1 = bt.y - ms.x * a1,
                d2 = bt.z - ms.x * a2, d3 = bt.w - ms.x * a3;
#pragma unroll
    for (int it = 0; it < 4; ++it) {
      const int no = nw + it * 16;
      const float v0 = ts[c4 * 4 + 0][no], v1 = ts[c4 * 4 + 1][no];
      const float v2 = ts[c4 * 4 + 2][no], v3 = ts[c4 * 4 + 3][no];
      s16x4 o = { f2bf(v0 * a0 + d0), f2bf(v1 * a1 + d1),
                  f2bf(v2 * a2 + d2), f2bf(v3 * a3 + d3) };
      *(s16x4*)(yT + ((size_t)b * 2304 + n0 + no) * 512 + cg) = o;
    }
  }
}

// ---------------- Generic bf16 MFMA GEMM (depth-3 ring) ---------------------
// D[M][N] = A[M][K] * Bt[N][K]^T, 128x128 tile, BK=32.
// EPI 0: bf16 + bias ; 1: f32 + bias + residual ; 2: bf16 no bias ;
// EPI 3: bf16 + bias[row], TILED vbuf store ([jb][cb][16][32], see top).
template <int EPI, bool BIASROW, int LDA, int LDB, int KSTEPS>
__global__ __launch_bounds__(256) void gemm_k(
    const short* __restrict__ A, size_t sA,
    const short* __restrict__ Bt, size_t sB,
    void* __restrict__ Dp, size_t sD,
    const float* __restrict__ bias, const float* __restrict__ resid,
    int N, int tilesM, int boff) {
  __shared__ short As[3][128 * 32];
  __shared__ short Bs[3][128 * 32];
  const int ba = blockIdx.y, bb = blockIdx.y + boff;
  int bx = blockIdx.x;
  bx = (bx & 7) * (int)(gridDim.x >> 3) + (bx >> 3);  // XCD-contiguous; grid.x % 8 == 0
  const int tm = bx % tilesM, tn = bx / tilesM;
  const int row0 = tm * 128, col0 = tn * 128;
  const int tid = threadIdx.x, lane = tid & 63, w = tid >> 6;
  const int lr = lane & 15, lg = lane >> 4;
  const short* Ab = A + (size_t)ba * sA;
  const short* Bb = Bt + (size_t)bb * sB;
  f32x4 acc[4][4];
  const f32x4 zero = {0.f, 0.f, 0.f, 0.f};
#pragma unroll
  for (int i = 0; i < 4; ++i)
#pragma unroll
    for (int j = 0; j < 4; ++j) acc[i][j] = zero;
  const int wrow = (w & 1) * 64, wcol = (w >> 1) * 64;
  const int sw = (lg ^ ((lr >> 1) & 3)) * 8;  // swizzled K-chunk (shorts)

#define GK_STAGE(KS, BUF)                                                      \
  {                                                                            \
    _Pragma("unroll")                                                          \
    for (int j = 0; j < 2; ++j) {                                              \
      const int g = (w * 2 + j) * 64 + lane; /* 16B chunks 0..511 */           \
      const int ko = (KS) * 32 + (((g & 3) ^ ((g >> 3) & 3)) * 8);             \
      const short* ga = Ab + (size_t)(row0 + (g >> 2)) * LDA + ko;             \
      const short* gb = Bb + (size_t)(col0 + (g >> 2)) * LDB + ko;             \
      __builtin_amdgcn_global_load_lds(                                        \
          (__attribute__((address_space(1))) void*)ga,                         \
          (__attribute__((address_space(3))) void*)&As[BUF][(w * 2 + j) * 512],\
          16, 0, 0);                                                           \
      __builtin_amdgcn_global_load_lds(                                        \
          (__attribute__((address_space(1))) void*)gb,                         \
          (__attribute__((address_space(3))) void*)&Bs[BUF][(w * 2 + j) * 512],\
          16, 0, 0);                                                           \
    }                                                                          \
  }

  GK_STAGE(0, 0);
  GK_STAGE(1, 1);
  GK_STAGE(2, 2);
  int cur = 0;
  for (int ks = 0; ks < KSTEPS; ++ks) {
    if (ks + 2 < KSTEPS)      WAITVM(8);   // 3 stages out: oldest landed
    else if (ks + 1 < KSTEPS) WAITVM(4);
    else                      WAITVM(0);
    __builtin_amdgcn_sched_barrier(0);
    __builtin_amdgcn_s_barrier();          // buf[cur] ready for all waves
    bf16x8 af[4], bfr[4];
#pragma unroll
    for (int mi = 0; mi < 4; ++mi)
      af[mi] = *(const bf16x8*)&As[cur][(wrow + mi * 16 + lr) * 32 + sw];
#pragma unroll
    for (int nj = 0; nj < 4; ++nj)
      bfr[nj] = *(const bf16x8*)&Bs[cur][(wcol + nj * 16 + lr) * 32 + sw];
    __builtin_amdgcn_s_setprio(1);
#pragma unroll
    for (int mi = 0; mi < 4; ++mi)
#pragma unroll
      for (int nj = 0; nj < 4; ++nj)
        acc[mi][nj] = __builtin_amdgcn_mfma_f32_16x16x32_bf16(af[mi], bfr[nj], acc[mi][nj], 0, 0, 0);
    __builtin_amdgcn_s_setprio(0);
    __builtin_amdgcn_s_barrier();          // all reads of buf[cur] done
    if (ks + 3 < KSTEPS) { GK_STAGE(ks + 3, cur) }   // refill freed buffer
    cur = (cur == 2) ? 0 : cur + 1;
  }
#undef GK_STAGE

  const size_t bD = (size_t)bb * sD;
  if (EPI == 3) {
    // tiled vbuf store: off = (jb*32 + c/16)*512 + (c%16)*32 + (j%32)
    const int colpos = col0 + wcol + lr * 4;
    const int jb = colpos >> 5, j5 = colpos & 31;
#pragma unroll
    for (int mi = 0; mi < 4; ++mi) {
#pragma unroll
      for (int r = 0; r < 4; ++r) {
        const int row = row0 + wrow + mi * 16 + lg * 4 + r;
        const float bv = bias[row];
        const int off = (jb * 32 + (row >> 4)) * 512 + ((row & 15) << 5) + j5;
        s16x4 o = { f2bf(acc[mi][0][r] + bv), f2bf(acc[mi][1][r] + bv),
                    f2bf(acc[mi][2][r] + bv), f2bf(acc[mi][3][r] + bv) };
        *(s16x4*)&((short*)Dp)[bD + off] = o;
      }
    }
  } else {
#pragma unroll
    for (int mi = 0; mi < 4; ++mi) {
#pragma unroll
      for (int nj = 0; nj < 4; ++nj) {
        const int col = col0 + wcol + nj * 16 + lr;
#pragma unroll
        for (int r = 0; r < 4; ++r) {
          const int row = row0 + wrow + mi * 16 + lg * 4 + r;
          float v = acc[mi][nj][r];
          if (EPI != 2) v += (BIASROW ? bias[row] : bias[col]);
          const size_t idx = bD + (size_t)row * N + col;
          if (EPI == 1) {
            ((float*)Dp)[idx] = v + resid[idx];
          } else {
            ((short*)Dp)[idx] = f2bf(v);
          }
        }
      }
    }
  }
}

// ---------------- S-GEMM, fixed-offset softmax epilogue ---------------------
// S[i][j] = z_i . y_j ; P = exp(S - 30) stored bf16, column-PERMUTED within
// 64-blocks (matches vbuf's j-permutation), packed 8B stores.
__global__ __launch_bounds__(256) void gemm_s(
    const short* __restrict__ z, const short* __restrict__ yT,
    short* __restrict__ Praw, float* __restrict__ Tsum, int b0) {
  __shared__ short As[3][128 * 32];
  __shared__ short Bs[3][128 * 32];
  const int cb = blockIdx.y;
  const int b = b0 + cb;
  int bx = blockIdx.x;                    // 324 tiles: bijective 8-way split (41/40)
  { const int xcd = bx & 7, id8 = bx >> 3;
    bx = (xcd < 4 ? xcd * 41 : 164 + (xcd - 4) * 40) + id8; }
  const int tm = bx % 18, tn = bx / 18;
  const int row0 = tm * 128, col0 = tn * 128;
  const int tid = threadIdx.x, lane = tid & 63, w = tid >> 6;
  const int lr = lane & 15, lg = lane >> 4;
  const short* Ab = z + (size_t)b * 2304 * 512;
  const short* Bb = yT + (size_t)b * 2304 * 512;
  f32x4 acc[4][4];
  const f32x4 zero = {0.f, 0.f, 0.f, 0.f};
#pragma unroll
  for (int i = 0; i < 4; ++i)
#pragma unroll
    for (int j = 0; j < 4; ++j) acc[i][j] = zero;
  const int wrow = (w & 1) * 64, wcol = (w >> 1) * 64;
  const int chalf = w >> 1;
  const int sw = (lg ^ ((lr >> 1) & 3)) * 8;

#define GS_STAGE(KS, BUF)                                                      \
  {                                                                            \
    _Pragma("unroll")                                                          \
    for (int j = 0; j < 2; ++j) {                                              \
      const int g = (w * 2 + j) * 64 + lane;                                   \
      const int ko = (KS) * 32 + (((g & 3) ^ ((g >> 3) & 3)) * 8);             \
      const short* ga = Ab + (size_t)(row0 + (g >> 2)) * 512 + ko;             \
      const short* gb = Bb + (size_t)(col0 + (g >> 2)) * 512 + ko;             \
      __builtin_amdgcn_global_load_lds(                                        \
          (__attribute__((address_space(1))) void*)ga,                         \
          (__attribute__((address_space(3))) void*)&As[BUF][(w * 2 + j) * 512],\
          16, 0, 0);                                                           \
      __builtin_amdgcn_global_load_lds(                                        \
          (__attribute__((address_space(1))) void*)gb,                         \
          (__attribute__((address_space(3))) void*)&Bs[BUF][(w * 2 + j) * 512],\
          16, 0, 0);                                                           \
    }                                                                          \
  }

  GS_STAGE(0, 0);
  GS_STAGE(1, 1);
  GS_STAGE(2, 2);
  int cur = 0;
  for (int ks = 0; ks < 16; ++ks) {
    if (ks < 14)      WAITVM(8);
    else if (ks < 15) WAITVM(4);
    else              WAITVM(0);
    __builtin_amdgcn_sched_barrier(0);
    __builtin_amdgcn_s_barrier();
    bf16x8 af[4], bfr[4];
#pragma unroll
    for (int mi = 0; mi < 4; ++mi)
      af[mi] = *(const bf16x8*)&As[cur][(wrow + mi * 16 + lr) * 32 + sw];
#pragma unroll
    for (int nj = 0; nj < 4; ++nj)
      bfr[nj] = *(const bf16x8*)&Bs[cur][(wcol + nj * 16 + lr) * 32 + sw];
    __builtin_amdgcn_s_setprio(1);
#pragma unroll
    for (int mi = 0; mi < 4; ++mi)
#pragma unroll
      for (int nj = 0; nj < 4; ++nj)
        acc[mi][nj] = __builtin_amdgcn_mfma_f32_16x16x32_bf16(af[mi], bfr[nj], acc[mi][nj], 0, 0, 0);
    __builtin_amdgcn_s_setprio(0);
    __builtin_amdgcn_s_barrier();
    if (ks + 3 < 16) { GS_STAGE(ks + 3, cur) }
    cur = (cur == 2) ? 0 : cur + 1;
  }
#undef GS_STAGE
  // epilogue: exp(acc-30), per-row partial sums, packed bf16 P store
  short* Pp = Praw + ((size_t)(cb * 18 + tn) * 2304 + row0) * 128;
  float* Ts = Tsum + (size_t)(cb * 2304 + row0) * 36 + tn * 2 + chalf;
#pragma unroll
  for (int mi = 0; mi < 4; ++mi) {
#pragma unroll
    for (int r = 0; r < 4; ++r) {
      const int row = wrow + mi * 16 + lg * 4 + r;
      float pv0 = __expf(acc[mi][0][r] - 30.f);
      float pv1 = __expf(acc[mi][1][r] - 30.f);
      float pv2 = __expf(acc[mi][2][r] - 30.f);
      float pv3 = __expf(acc[mi][3][r] - 30.f);
      float sum = pv0 + pv1 + pv2 + pv3;
#pragma unroll
      for (int d = 1; d < 16; d <<= 1) sum += __shfl_xor(sum, d);
      if (lr == 0) Ts[(size_t)row * 36] = sum;
      s16x4 o = { f2bf(pv0), f2bf(pv1), f2bf(pv2), f2bf(pv3) };
      *(s16x4*)(Pp + (size_t)row * 128 + wcol + lr * 4) = o;
    }
  }
}

// ---------------- linv[row] = 1 / sum_t Tsum[row][t] ------------------------
__global__ __launch_bounds__(256) void sum_k(
    const float* __restrict__ Tsum, float* __restrict__ linv, int nrows) {
  const int r = blockIdx.x * 256 + threadIdx.x;
  if (r >= nrows) return;
  const float* ts = Tsum + (size_t)r * 36;
  float l = 0.f;
#pragma unroll
  for (int t = 0; t < 36; ++t) l += ts[t];
  linv[r] = 1.f / l;
}

// ---------------- PV GEMM (R5 structure + tiled-V loads) --------------------
// oT[i][c] = linv[i] * sum_j Praw[i][j] * v[c][j]  (j,c in permuted space)
// 16 tm-tiles x 16 batches = 256 blocks = exactly 1 block/CU (R5's proven
// lever). 8 waves; wave w owns c-slice [64w,64w+64). A (P) staged in LDS
// depth-3 ring; V loads from the TILED vbuf: each bf16x8 instruction now
// reads 1024 B contiguous (was 16 lines scattered at 4608 B stride ->
// L2-channel camping, the suspected ~10 B/cy/CU vmem ceiling).
__global__ __launch_bounds__(512) void gemm_pv(
    const short* __restrict__ Praw, const float* __restrict__ linv,
    const short* __restrict__ vsrc, short* __restrict__ Dp, int b0) {
  __shared__ short As[3][144 * 32];   // 3 x 9 KB
  int tm, cb;
  if (gridDim.y == 16) {
    const int id = blockIdx.y * 16 + blockIdx.x;   // 256 blocks
    const int xcd = id & 7, r = id >> 3;           // r in [0,32)
    cb = xcd * 2 + (r >= 16 ? 1 : 0);
    tm = r & 15;
  } else {
    cb = blockIdx.y; tm = blockIdx.x;
  }
  const int bb = b0 + cb;
  const int row0 = tm * 144;
  const int tid = threadIdx.x, lane = tid & 63, w = tid >> 6;  // 8 waves
  const int lr = lane & 15, lg = lane >> 4;
  const short* Ab = Praw + (size_t)cb * 18 * 2304 * 128;
  const short* Bb = vsrc + (size_t)bb * 512 * 2304;
  // tiled-V fragment pointers: off = (ks*32 + w*4+nj)*512 + lr*32 + lg*8
  const short* Bp0 = Bb + (w * 4 + 0) * 512 + lr * 32 + lg * 8;
  const short* Bp1 = Bb + (w * 4 + 1) * 512 + lr * 32 + lg * 8;
  const short* Bp2 = Bb + (w * 4 + 2) * 512 + lr * 32 + lg * 8;
  const short* Bp3 = Bb + (w * 4 + 3) * 512 + lr * 32 + lg * 8;
  f32x4 acc[9][4];
  const f32x4 zero = {0.f, 0.f, 0.f, 0.f};
#pragma unroll
  for (int i = 0; i < 9; ++i)
#pragma unroll
    for (int j = 0; j < 4; ++j) acc[i][j] = zero;
  const int sw = (lg ^ ((lr >> 1) & 3)) * 8;

  // A stage: 144x32 tile = 576 x 16B chunks; threads stage chunk tid, and
  // wave 0 additionally stages chunks 512+lane (rows 128..143).
#define PVA_STAGE(KS, BUF)                                                     \
  {                                                                            \
    const int kt = (KS) >> 2, k32 = ((KS) & 3) * 32;                           \
    {                                                                          \
      const int g = tid;                                                       \
      const short* ga = Ab + ((size_t)kt * 2304 + row0 + (g >> 2)) * 128 +     \
                        k32 + (((g & 3) ^ ((g >> 3) & 3)) * 8);                \
      __builtin_amdgcn_global_load_lds(                                        \
          (__attribute__((address_space(1))) void*)ga,                         \
          (__attribute__((address_space(3))) void*)&As[BUF][w * 512], 16,0,0); \
    }                                                                          \
    if (w == 0) {                                                              \
      const int g = 512 + tid;                                                 \
      const short* ga = Ab + ((size_t)kt * 2304 + row0 + (g >> 2)) * 128 +     \
                        k32 + (((g & 3) ^ ((g >> 3) & 3)) * 8);                \
      __builtin_amdgcn_global_load_lds(                                        \
          (__attribute__((address_space(1))) void*)ga,                         \
          (__attribute__((address_space(3))) void*)&As[BUF][4096], 16, 0, 0);  \
    }                                                                          \
  }

#define PV_BLOAD(KS, BR)                                                       \
  {                                                                            \
    BR[0] = *(const bf16x8*)(Bp0 + (KS) * 16384);                              \
    BR[1] = *(const bf16x8*)(Bp1 + (KS) * 16384);                              \
    BR[2] = *(const bf16x8*)(Bp2 + (KS) * 16384);                              \
    BR[3] = *(const bf16x8*)(Bp3 + (KS) * 16384);                              \
  }

  // Steady outstanding at iter top (oldest first), wave 0 / waves 1-7:
  //   A(ks)2/1, B(ks)4, A(ks+1)2/1, B(ks+1)4, A(ks+2)2/1 = 14 / 11
  // -> WAITVM(12)/(10) retires exactly A(ks). Compiler waits cover B regs.
#define PV_ITER(KS, BUSE, BFILL)                                               \
  {                                                                            \
    if ((KS) < 70)       { if (w == 0) WAITVM(12); else WAITVM(10); }          \
    else if ((KS) == 70) { if (w == 0) WAITVM(10); else WAITVM(8); }           \
    else                 WAITVM(4);                                            \
    __builtin_amdgcn_sched_barrier(0);                                         \
    __builtin_amdgcn_s_barrier();                                              \
    bf16x8 af[9];                                                              \
    _Pragma("unroll")                                                          \
    for (int mi = 0; mi < 9; ++mi)                                             \
      af[mi] = *(const bf16x8*)&As[cur][(mi * 16 + lr) * 32 + sw];             \
    __builtin_amdgcn_s_setprio(1);                                             \
    _Pragma("unroll")                                                          \
    for (int mi = 0; mi < 9; ++mi)                                             \
      _Pragma("unroll")                                                        \
      for (int nj = 0; nj < 4; ++nj)                                           \
        acc[mi][nj] = __builtin_amdgcn_mfma_f32_16x16x32_bf16(                 \
            af[mi], BUSE[nj], acc[mi][nj], 0, 0, 0);                           \
    __builtin_amdgcn_s_setprio(0);                                             \
    __builtin_amdgcn_s_barrier();                                              \
    if ((KS) + 2 < 72) PV_BLOAD((KS) + 2, BFILL);                              \
    if ((KS) + 3 < 72) PVA_STAGE((KS) + 3, cur);                               \
    cur = (cur == 2) ? 0 : cur + 1;                                            \
  }

  bf16x8 bA[4], bB[4];
  PVA_STAGE(0, 0);
  PVA_STAGE(1, 1);
  PVA_STAGE(2, 2);
  PV_BLOAD(0, bA);
  PV_BLOAD(1, bB);
  int cur = 0;
  for (int ks = 0; ks < 72; ks += 2) {
    PV_ITER(ks, bA, bA);
    PV_ITER(ks + 1, bB, bB);
  }
#undef PV_ITER
#undef PV_BLOAD
#undef PVA_STAGE

  const float* lv = linv + (size_t)cb * 2304 + row0;
  short* Db = Dp + (size_t)bb * 2304 * 512;
#pragma unroll
  for (int mi = 0; mi < 9; ++mi) {
#pragma unroll
    for (int r = 0; r < 4; ++r) {
      const int row = mi * 16 + lg * 4 + r;
      const float s = lv[row];
      s16x4 o = { f2bf(acc[mi][0][r] * s), f2bf(acc[mi][1][r] * s),
                  f2bf(acc[mi][2][r] * s), f2bf(acc[mi][3][r] * s) };
      // c-permuted within 64-block (matches Wo): position = w*64 + lr*4 + nj
      *(s16x4*)(Db + (size_t)(row0 + row) * 512 + w * 64 + lr * 4) = o;
    }
  }
}

// ---------------- launcher ---------------------------------------------------
extern "C" void kernel_launch(void* const* d_in, const int* in_sizes, int n_in,
                              void* d_out, int out_size, void* d_ws, size_t ws_size,
                              hipStream_t stream) {
  const float* x     = (const float*)d_in[0];
  const float* gamma = (const float*)d_in[1];
  const float* beta  = (const float*)d_in[2];
  const float* wq    = (const float*)d_in[3];
  const float* bq    = (const float*)d_in[4];
  const float* wk    = (const float*)d_in[5];
  // d_in[6] = bk: unused (per-row constant, cancels in softmax)
  const float* wv    = (const float*)d_in[7];
  const float* bv    = (const float*)d_in[8];
  const float* wo    = (const float*)d_in[9];
  const float* bo    = (const float*)d_in[10];

  char* ws = (char*)d_ws;
  float2* stats = (float2*)(ws + 0);
  short*  Wv    = (short*)(ws + 8192);
  short*  Wo    = (short*)(ws + 532480);
  short*  WkT   = (short*)(ws + 1056768);
  short*  WqT   = (short*)(ws + 1581056);
  short*  G     = (short*)(ws + 2105344);
  float*  g0    = (float*)(ws + 2629632);
  short*  yT    = (short*)(ws + 2631680);     //  36 MB  [B][2304][512]
  short*  zoT   = (short*)(ws + 40380416);    //  36 MB  z, overwritten by oT
  short*  vbuf  = (short*)(ws + 78129152);    //  36 MB  [B][72][32][16][32] tiled
  short*  Praw  = (short*)(ws + 115877888);   //  CH * 10,616,832 [b][18][2304][128]
  float*  out   = (float*)d_out;

  const size_t base = 115877888ull;
  const size_t per  = 10616832ull + 331776ull + 9216ull;  // Praw+Tsum+linv
  int CH = 16;
  if (ws_size < base + 16 * per) CH = (ws_size >= base + 8 * per) ? 8 : 4;
  float* Tsum = (float*)(ws + base + (size_t)CH * 10616832ull);
  float* linv = (float*)(ws + base + (size_t)CH * (10616832ull + 331776ull));

  const size_t sBN = (size_t)2304 * 512;

  prep_k<<<1024, 256, 0, stream>>>(wq, wk, wv, wo, Wv, Wo, WkT, WqT);
  g0_k<<<2, 256, 0, stream>>>(wk, bq, g0);
  gn_stats<<<512, 256, 0, stream>>>(x, stats);
  gn_norm_t<<<dim3(36, 8, 16), 256, 0, stream>>>(x, stats, gamma, beta, yT);
  // G[c'][c] = sum_o WkT[c'][o] * WqT[c][o]
  gemm_k<2, false, 512, 512, 16><<<dim3(16, 1), 256, 0, stream>>>(
      WkT, 0, WqT, 0, G, 0, nullptr, nullptr, 512, 4, 0);
  // v[b][o][n] = sum_c Wv[o][c] * yT[b][n][c] + bv[o]  (tiled store)
  gemm_k<3, true, 512, 512, 16><<<dim3(72, 16), 256, 0, stream>>>(
      Wv, 0, yT, sBN, vbuf, sBN, bv, nullptr, 2304, 4, 0);
  // z[b][i][c'] = sum_c yT[b][i][c] * G[c'][c] + g0[c']
  gemm_k<0, false, 512, 512, 16><<<dim3(72, 16), 256, 0, stream>>>(
      yT, sBN, G, 0, zoT, sBN, g0, nullptr, 512, 18, 0);

  for (int b0 = 0; b0 < 16; b0 += CH) {
    const int n = (16 - b0 < CH) ? (16 - b0) : CH;
    gemm_s<<<dim3(324, n), 256, 0, stream>>>(zoT, yT, Praw, Tsum, b0);
    sum_k<<<(n * 2304 + 255) / 256, 256, 0, stream>>>(Tsum, linv, n * 2304);
    gemm_pv<<<dim3(16, n), 512, 0, stream>>>(Praw, linv, vbuf, zoT, b0);
  }
  // out[b][o][n] = sum_c Wo[o][c] * oT[b][n][c] + bo[o] + x[b][o][n]
  // (c-permutation on both Wo and oT cancels in the contraction)
  gemm_k<1, true, 512, 512, 16><<<dim3(72, 16), 256, 0, stream>>>(
      Wo, 0, zoT, sBN, out, (size_t)512 * 2304, bo, x, 2304, 4, 0);
}

// Round 9
// 429.734 us; speedup vs baseline: 1.6855x; 1.0281x over previous
//
#include <hip/hip_runtime.h>

#define DI __device__ __forceinline__

typedef __attribute__((ext_vector_type(8))) short bf16x8;
typedef __attribute__((ext_vector_type(4))) short s16x4;
typedef __attribute__((ext_vector_type(4))) float f32x4;

DI short f2bf(float f) {
  unsigned u = __builtin_bit_cast(unsigned, f);
  u += 0x7FFFu + ((u >> 16) & 1u);
  return (short)(u >> 16);
}

#define WAITVM(N) asm volatile("s_waitcnt vmcnt(" #N ")" ::: "memory")

// Within-64 column permutation used for packed epilogues:
//   position p holds true column c:  p = (c&~63) + (c&15)*4 + ((c>>4)&3)
// Applied consistently to {P cols, vbuf j} (PV contraction) and
// {Wo cols, oT cols} (output-GEMM contraction) -> cancels algebraically.
//
// R8: vbuf tiled [jb=72][cb=32][16][32] -> PV B-loads 1KB contiguous (+30%).
// R9: SAME mechanism everywhere. All bf16 [n][512] intermediates (yT, z, oT,
// G, Wv, Wo) stored K-chunk-tiled:
//   off(n,k) = (n>>7)*65536 + (k>>5)*4096 + (n&127)*32 + (k&31)
// so every GEMM staging instruction reads 1KB contiguous instead of 16 lines
// at 1024B stride (the L2-channel-camping pattern R8 proved costly).
// Staging addr for a 128-aligned tile: base + row0*512 + KS*4096 + chunk*32.

// ---------------- prep: weights -> bf16 (+ transposed Wk/Wq for G) ----------
__global__ __launch_bounds__(256) void prep_k(
    const float* __restrict__ wq, const float* __restrict__ wk,
    const float* __restrict__ wv, const float* __restrict__ wo,
    short* __restrict__ Wv, short* __restrict__ Wo,
    short* __restrict__ WkT, short* __restrict__ WqT) {
  const int i = blockIdx.x * 256 + threadIdx.x;  // 0..262143
  const float sc = 0.04419417382415922f;         // 1/sqrt(512)
  const int o = i >> 9, c = i & 511;
  // tiled stores (row=o, col=c / col=cp)
  Wv[(o >> 7) * 65536 + (c >> 5) * 4096 + (o & 127) * 32 + (c & 31)] = f2bf(wv[i]);
  const int cp = (c & ~63) | ((c & 15) << 2) | ((c >> 4) & 3);
  Wo[(o >> 7) * 65536 + (cp >> 5) * 4096 + (o & 127) * 32 + (cp & 31)] = f2bf(wo[i]);
  const int tr = c * 512 + o;
  WkT[tr] = f2bf(wk[i] * sc);   // scale folded into Wk side (linear, small)
  WqT[tr] = f2bf(wq[i]);
}

// ---------------- g0[c'] = s * sum_o wk[o][c'] * bq[o] ----------------------
__global__ __launch_bounds__(256) void g0_k(const float* __restrict__ wk,
                                            const float* __restrict__ bq,
                                            float* __restrict__ g0) {
  const int c = blockIdx.x * 256 + threadIdx.x;  // 0..511
  float acc = 0.f;
#pragma unroll 8
  for (int o = 0; o < 512; ++o) acc += wk[o * 512 + c] * bq[o];
  g0[c] = acc * 0.04419417382415922f;
}

// ---------------- GroupNorm pass 1: per (b,g) mean/rstd ---------------------
__global__ __launch_bounds__(256) void gn_stats(const float* __restrict__ x,
                                                float2* __restrict__ stats) {
  const int bg = blockIdx.x;
  const float4* xg = (const float4*)(x + (size_t)bg * 36864);
  float s = 0.f, q = 0.f;
  for (int i = threadIdx.x; i < 9216; i += 256) {
    float4 v = xg[i];
    s += v.x + v.y + v.z + v.w;
    q += v.x * v.x + v.y * v.y + v.z * v.z + v.w * v.w;
  }
#pragma unroll
  for (int d = 1; d < 64; d <<= 1) { s += __shfl_xor(s, d); q += __shfl_xor(q, d); }
  __shared__ float rs[4], rq[4];
  const int w = threadIdx.x >> 6;
  if ((threadIdx.x & 63) == 0) { rs[w] = s; rq[w] = q; }
  __syncthreads();
  if (threadIdx.x == 0) {
    float S = rs[0] + rs[1] + rs[2] + rs[3];
    float Q = rq[0] + rq[1] + rq[2] + rq[3];
    float mean = S * (1.f / 36864.f);
    float var  = Q * (1.f / 36864.f) - mean * mean;
    float2 o; o.x = mean; o.y = rsqrtf(var + 1e-5f);
    stats[bg] = o;
  }
}

// ---------------- GroupNorm pass 2: normalize + transpose -> yT bf16 --------
__global__ __launch_bounds__(256) void gn_norm_t(
    const float* __restrict__ x, const float2* __restrict__ stats,
    const float* __restrict__ gamma, const float* __restrict__ beta,
    short* __restrict__ yT) {
  __shared__ float ts[64][68];
  const int n0 = blockIdx.x * 64, c0 = blockIdx.y * 64, b = blockIdx.z;
  const int t = threadIdx.x;
  {
    const int cw = t >> 4;
    const int n4 = (t & 15) * 4;
    const float* xb = x + ((size_t)b * 512 + c0) * 2304 + n0;
#pragma unroll
    for (int r4 = 0; r4 < 4; ++r4) {
      const int c = cw + r4 * 16;
      float4 v = *(const float4*)(xb + (size_t)c * 2304 + n4);
      *(float4*)&ts[c][n4] = v;
    }
  }
  __syncthreads();
  {
    const int c4 = t & 15;
    const int nw = t >> 4;
    const int cg = c0 + c4 * 4;
    const float2 ms = stats[b * 32 + (cg >> 4)];
    const float4 gm = *(const float4*)(gamma + cg);
    const float4 bt = *(const float4*)(beta + cg);
    const float a0 = ms.y * gm.x, a1 = ms.y * gm.y, a2 = ms.y * gm.z, a3 = ms.y * gm.w;
    const float d0 = bt.x - ms.x * a0, d1 = bt.y - ms.x * a1,
                d2 = bt.z - ms.x * a2, d3 = bt.w - ms.x * a3;
#pragma unroll
    for (int it = 0; it < 4; ++it) {
      const int no = nw + it * 16;
      const int n = n0 + no;
      const float v0 = ts[c4 * 4 + 0][no], v1 = ts[c4 * 4 + 1][no];
      const float v2 = ts[c4 * 4 + 2][no], v3 = ts[c4 * 4 + 3][no];
      s16x4 o = { f2bf(v0 * a0 + d0), f2bf(v1 * a1 + d1),
                  f2bf(v2 * a2 + d2), f2bf(v3 * a3 + d3) };
      // tiled yT store: off(n, cg)
      *(s16x4*)(yT + (size_t)b * 2304 * 512 + (n >> 7) * 65536 +
                (cg >> 5) * 4096 + (n & 127) * 32 + (cg & 31)) = o;
    }
  }
}

// ---------------- Generic bf16 MFMA GEMM (depth-3 ring) ---------------------
// D[M][N] = A[M][K] * Bt[N][K]^T, 128x128 tile, BK=32.
// AT/BT: operand stored K-chunk-tiled (1KB-contiguous staging reads).
// DT: bf16 output stored K-chunk-tiled.
// EPI 0: bf16 + bias ; 1: f32 + bias + residual (linear, final out) ;
// EPI 2: bf16 no bias ; 3: bf16 + bias[row], vbuf-tiled store (R8).
template <int EPI, bool BIASROW, bool AT, bool BT, bool DT, int LDA, int LDB,
          int KSTEPS>
__global__ __launch_bounds__(256) void gemm_k(
    const short* __restrict__ A, size_t sA,
    const short* __restrict__ Bt, size_t sB,
    void* __restrict__ Dp, size_t sD,
    const float* __restrict__ bias, const float* __restrict__ resid,
    int N, int tilesM, int boff) {
  __shared__ short As[3][128 * 32];
  __shared__ short Bs[3][128 * 32];
  const int ba = blockIdx.y, bb = blockIdx.y + boff;
  int bx = blockIdx.x;
  bx = (bx & 7) * (int)(gridDim.x >> 3) + (bx >> 3);  // XCD-contiguous; grid.x % 8 == 0
  const int tm = bx % tilesM, tn = bx / tilesM;
  const int row0 = tm * 128, col0 = tn * 128;
  const int tid = threadIdx.x, lane = tid & 63, w = tid >> 6;
  const int lr = lane & 15, lg = lane >> 4;
  const short* Ab = A + (size_t)ba * sA;
  const short* Bb = Bt + (size_t)bb * sB;
  f32x4 acc[4][4];
  const f32x4 zero = {0.f, 0.f, 0.f, 0.f};
#pragma unroll
  for (int i = 0; i < 4; ++i)
#pragma unroll
    for (int j = 0; j < 4; ++j) acc[i][j] = zero;
  const int wrow = (w & 1) * 64, wcol = (w >> 1) * 64;
  const int sw = (lg ^ ((lr >> 1) & 3)) * 8;  // swizzled K-chunk (shorts)

#define GK_STAGE(KS, BUF)                                                      \
  {                                                                            \
    _Pragma("unroll")                                                          \
    for (int j = 0; j < 2; ++j) {                                              \
      const int g = (w * 2 + j) * 64 + lane; /* 16B chunks 0..511 */           \
      const int sub8 = ((g & 3) ^ ((g >> 3) & 3)) * 8;                         \
      const short* ga = AT ? (Ab + (size_t)row0 * 512 + (KS) * 4096 +          \
                              (g >> 2) * 32 + sub8)                            \
                           : (Ab + (size_t)(row0 + (g >> 2)) * LDA +           \
                              (KS) * 32 + sub8);                               \
      const short* gb = BT ? (Bb + (size_t)col0 * 512 + (KS) * 4096 +          \
                              (g >> 2) * 32 + sub8)                            \
                           : (Bb + (size_t)(col0 + (g >> 2)) * LDB +           \
                              (KS) * 32 + sub8);                               \
      __builtin_amdgcn_global_load_lds(                                        \
          (__attribute__((address_space(1))) void*)ga,                         \
          (__attribute__((address_space(3))) void*)&As[BUF][(w * 2 + j) * 512],\
          16, 0, 0);                                                           \
      __builtin_amdgcn_global_load_lds(                                        \
          (__attribute__((address_space(1))) void*)gb,                         \
          (__attribute__((address_space(3))) void*)&Bs[BUF][(w * 2 + j) * 512],\
          16, 0, 0);                                                           \
    }                                                                          \
  }

  GK_STAGE(0, 0);
  GK_STAGE(1, 1);
  GK_STAGE(2, 2);
  int cur = 0;
  for (int ks = 0; ks < KSTEPS; ++ks) {
    if (ks + 2 < KSTEPS)      WAITVM(8);   // 3 stages out: oldest landed
    else if (ks + 1 < KSTEPS) WAITVM(4);
    else                      WAITVM(0);
    __builtin_amdgcn_sched_barrier(0);
    __builtin_amdgcn_s_barrier();          // buf[cur] ready for all waves
    bf16x8 af[4], bfr[4];
#pragma unroll
    for (int mi = 0; mi < 4; ++mi)
      af[mi] = *(const bf16x8*)&As[cur][(wrow + mi * 16 + lr) * 32 + sw];
#pragma unroll
    for (int nj = 0; nj < 4; ++nj)
      bfr[nj] = *(const bf16x8*)&Bs[cur][(wcol + nj * 16 + lr) * 32 + sw];
    __builtin_amdgcn_s_setprio(1);
#pragma unroll
    for (int mi = 0; mi < 4; ++mi)
#pragma unroll
      for (int nj = 0; nj < 4; ++nj)
        acc[mi][nj] = __builtin_amdgcn_mfma_f32_16x16x32_bf16(af[mi], bfr[nj], acc[mi][nj], 0, 0, 0);
    __builtin_amdgcn_s_setprio(0);
    __builtin_amdgcn_s_barrier();          // all reads of buf[cur] done
    if (ks + 3 < KSTEPS) { GK_STAGE(ks + 3, cur) }   // refill freed buffer
    cur = (cur == 2) ? 0 : cur + 1;
  }
#undef GK_STAGE

  const size_t bD = (size_t)bb * sD;
  if (EPI == 3) {
    // vbuf-tiled store: off = (jb*32 + c/16)*512 + (c%16)*32 + (j%32)
    const int colpos = col0 + wcol + lr * 4;
    const int jb = colpos >> 5, j5 = colpos & 31;
#pragma unroll
    for (int mi = 0; mi < 4; ++mi) {
#pragma unroll
      for (int r = 0; r < 4; ++r) {
        const int row = row0 + wrow + mi * 16 + lg * 4 + r;
        const float bv = bias[row];
        const int off = (jb * 32 + (row >> 4)) * 512 + ((row & 15) << 5) + j5;
        s16x4 o = { f2bf(acc[mi][0][r] + bv), f2bf(acc[mi][1][r] + bv),
                    f2bf(acc[mi][2][r] + bv), f2bf(acc[mi][3][r] + bv) };
        *(s16x4*)&((short*)Dp)[bD + off] = o;
      }
    }
  } else {
#pragma unroll
    for (int mi = 0; mi < 4; ++mi) {
#pragma unroll
      for (int nj = 0; nj < 4; ++nj) {
        const int col = col0 + wcol + nj * 16 + lr;
#pragma unroll
        for (int r = 0; r < 4; ++r) {
          const int row = row0 + wrow + mi * 16 + lg * 4 + r;
          float v = acc[mi][nj][r];
          if (EPI != 2) v += (BIASROW ? bias[row] : bias[col]);
          if (EPI == 1) {
            const size_t idx = bD + (size_t)row * N + col;
            ((float*)Dp)[idx] = v + resid[idx];
          } else {
            const size_t idx = bD + (DT
                ? (size_t)((row >> 7) * 65536 + (col >> 5) * 4096 +
                           (row & 127) * 32 + (col & 31))
                : (size_t)row * N + col);
            ((short*)Dp)[idx] = f2bf(v);
          }
        }
      }
    }
  }
}

// ---------------- S-GEMM, fixed-offset softmax epilogue ---------------------
// S[i][j] = z_i . y_j ; P = exp(S - 30) stored bf16, column-PERMUTED within
// 64-blocks (matches vbuf's j-permutation), packed 8B stores.
// R9: z and yT are K-chunk-tiled -> staging reads 1KB contiguous.
__global__ __launch_bounds__(256) void gemm_s(
    const short* __restrict__ z, const short* __restrict__ yT,
    short* __restrict__ Praw, float* __restrict__ Tsum, int b0) {
  __shared__ short As[3][128 * 32];
  __shared__ short Bs[3][128 * 32];
  const int cb = blockIdx.y;
  const int b = b0 + cb;
  int bx = blockIdx.x;                    // 324 tiles: bijective 8-way split (41/40)
  { const int xcd = bx & 7, id8 = bx >> 3;
    bx = (xcd < 4 ? xcd * 41 : 164 + (xcd - 4) * 40) + id8; }
  const int tm = bx % 18, tn = bx / 18;
  const int row0 = tm * 128, col0 = tn * 128;
  const int tid = threadIdx.x, lane = tid & 63, w = tid >> 6;
  const int lr = lane & 15, lg = lane >> 4;
  const short* Ab = z + (size_t)b * 2304 * 512;
  const short* Bb = yT + (size_t)b * 2304 * 512;
  f32x4 acc[4][4];
  const f32x4 zero = {0.f, 0.f, 0.f, 0.f};
#pragma unroll
  for (int i = 0; i < 4; ++i)
#pragma unroll
    for (int j = 0; j < 4; ++j) acc[i][j] = zero;
  const int wrow = (w & 1) * 64, wcol = (w >> 1) * 64;
  const int chalf = w >> 1;
  const int sw = (lg ^ ((lr >> 1) & 3)) * 8;

#define GS_STAGE(KS, BUF)                                                      \
  {                                                                            \
    _Pragma("unroll")                                                          \
    for (int j = 0; j < 2; ++j) {                                              \
      const int g = (w * 2 + j) * 64 + lane;                                   \
      const int sub8 = ((g & 3) ^ ((g >> 3) & 3)) * 8;                         \
      const short* ga = Ab + (size_t)row0 * 512 + (KS) * 4096 +                \
                        (g >> 2) * 32 + sub8;                                  \
      const short* gb = Bb + (size_t)col0 * 512 + (KS) * 4096 +                \
                        (g >> 2) * 32 + sub8;                                  \
      __builtin_amdgcn_global_load_lds(                                        \
          (__attribute__((address_space(1))) void*)ga,                         \
          (__attribute__((address_space(3))) void*)&As[BUF][(w * 2 + j) * 512],\
          16, 0, 0);                                                           \
      __builtin_amdgcn_global_load_lds(                                        \
          (__attribute__((address_space(1))) void*)gb,                         \
          (__attribute__((address_space(3))) void*)&Bs[BUF][(w * 2 + j) * 512],\
          16, 0, 0);                                                           \
    }                                                                          \
  }

  GS_STAGE(0, 0);
  GS_STAGE(1, 1);
  GS_STAGE(2, 2);
  int cur = 0;
  for (int ks = 0; ks < 16; ++ks) {
    if (ks < 14)      WAITVM(8);
    else if (ks < 15) WAITVM(4);
    else              WAITVM(0);
    __builtin_amdgcn_sched_barrier(0);
    __builtin_amdgcn_s_barrier();
    bf16x8 af[4], bfr[4];
#pragma unroll
    for (int mi = 0; mi < 4; ++mi)
      af[mi] = *(const bf16x8*)&As[cur][(wrow + mi * 16 + lr) * 32 + sw];
#pragma unroll
    for (int nj = 0; nj < 4; ++nj)
      bfr[nj] = *(const bf16x8*)&Bs[cur][(wcol + nj * 16 + lr) * 32 + sw];
    __builtin_amdgcn_s_setprio(1);
#pragma unroll
    for (int mi = 0; mi < 4; ++mi)
#pragma unroll
      for (int nj = 0; nj < 4; ++nj)
        acc[mi][nj] = __builtin_amdgcn_mfma_f32_16x16x32_bf16(af[mi], bfr[nj], acc[mi][nj], 0, 0, 0);
    __builtin_amdgcn_s_setprio(0);
    __builtin_amdgcn_s_barrier();
    if (ks + 3 < 16) { GS_STAGE(ks + 3, cur) }
    cur = (cur == 2) ? 0 : cur + 1;
  }
#undef GS_STAGE
  // epilogue: exp(acc-30), per-row partial sums, packed bf16 P store
  short* Pp = Praw + ((size_t)(cb * 18 + tn) * 2304 + row0) * 128;
  float* Ts = Tsum + (size_t)(cb * 2304 + row0) * 36 + tn * 2 + chalf;
#pragma unroll
  for (int mi = 0; mi < 4; ++mi) {
#pragma unroll
    for (int r = 0; r < 4; ++r) {
      const int row = wrow + mi * 16 + lg * 4 + r;
      float pv0 = __expf(acc[mi][0][r] - 30.f);
      float pv1 = __expf(acc[mi][1][r] - 30.f);
      float pv2 = __expf(acc[mi][2][r] - 30.f);
      float pv3 = __expf(acc[mi][3][r] - 30.f);
      float sum = pv0 + pv1 + pv2 + pv3;
#pragma unroll
      for (int d = 1; d < 16; d <<= 1) sum += __shfl_xor(sum, d);
      if (lr == 0) Ts[(size_t)row * 36] = sum;
      s16x4 o = { f2bf(pv0), f2bf(pv1), f2bf(pv2), f2bf(pv3) };
      *(s16x4*)(Pp + (size_t)row * 128 + wcol + lr * 4) = o;
    }
  }
}

// ---------------- linv[row] = 1 / sum_t Tsum[row][t] ------------------------
__global__ __launch_bounds__(256) void sum_k(
    const float* __restrict__ Tsum, float* __restrict__ linv, int nrows) {
  const int r = blockIdx.x * 256 + threadIdx.x;
  if (r >= nrows) return;
  const float* ts = Tsum + (size_t)r * 36;
  float l = 0.f;
#pragma unroll
  for (int t = 0; t < 36; ++t) l += ts[t];
  linv[r] = 1.f / l;
}

// ---------------- PV GEMM (R5 structure + tiled-V loads, R8) ----------------
// oT[i][c] = linv[i] * sum_j Praw[i][j] * v[c][j]  (j,c in permuted space)
// 16 tm-tiles x 16 batches = 256 blocks = exactly 1 block/CU. 8 waves; wave w
// owns c-slice [64w,64w+64). A (P) staged in LDS depth-3 ring; V loads from
// tiled vbuf (1KB contiguous). R9: oT stored K-chunk-tiled for the out-GEMM.
__global__ __launch_bounds__(512) void gemm_pv(
    const short* __restrict__ Praw, const float* __restrict__ linv,
    const short* __restrict__ vsrc, short* __restrict__ Dp, int b0) {
  __shared__ short As[3][144 * 32];   // 3 x 9 KB
  int tm, cb;
  if (gridDim.y == 16) {
    const int id = blockIdx.y * 16 + blockIdx.x;   // 256 blocks
    const int xcd = id & 7, r = id >> 3;           // r in [0,32)
    cb = xcd * 2 + (r >= 16 ? 1 : 0);
    tm = r & 15;
  } else {
    cb = blockIdx.y; tm = blockIdx.x;
  }
  const int bb = b0 + cb;
  const int row0 = tm * 144;
  const int tid = threadIdx.x, lane = tid & 63, w = tid >> 6;  // 8 waves
  const int lr = lane & 15, lg = lane >> 4;
  const short* Ab = Praw + (size_t)cb * 18 * 2304 * 128;
  const short* Bb = vsrc + (size_t)bb * 512 * 2304;
  // tiled-V fragment pointers: off = (ks*32 + w*4+nj)*512 + lr*32 + lg*8
  const short* Bp0 = Bb + (w * 4 + 0) * 512 + lr * 32 + lg * 8;
  const short* Bp1 = Bb + (w * 4 + 1) * 512 + lr * 32 + lg * 8;
  const short* Bp2 = Bb + (w * 4 + 2) * 512 + lr * 32 + lg * 8;
  const short* Bp3 = Bb + (w * 4 + 3) * 512 + lr * 32 + lg * 8;
  f32x4 acc[9][4];
  const f32x4 zero = {0.f, 0.f, 0.f, 0.f};
#pragma unroll
  for (int i = 0; i < 9; ++i)
#pragma unroll
    for (int j = 0; j < 4; ++j) acc[i][j] = zero;
  const int sw = (lg ^ ((lr >> 1) & 3)) * 8;

  // A stage: 144x32 tile = 576 x 16B chunks; threads stage chunk tid, and
  // wave 0 additionally stages chunks 512+lane (rows 128..143).
#define PVA_STAGE(KS, BUF)                                                     \
  {                                                                            \
    const int kt = (KS) >> 2, k32 = ((KS) & 3) * 32;                           \
    {                                                                          \
      const int g = tid;                                                       \
      const short* ga = Ab + ((size_t)kt * 2304 + row0 + (g >> 2)) * 128 +     \
                        k32 + (((g & 3) ^ ((g >> 3) & 3)) * 8);                \
      __builtin_amdgcn_global_load_lds(                                        \
          (__attribute__((address_space(1))) void*)ga,                         \
          (__attribute__((address_space(3))) void*)&As[BUF][w * 512], 16,0,0); \
    }                                                                          \
    if (w == 0) {                                                              \
      const int g = 512 + tid;                                                 \
      const short* ga = Ab + ((size_t)kt * 2304 + row0 + (g >> 2)) * 128 +     \
                        k32 + (((g & 3) ^ ((g >> 3) & 3)) * 8);                \
      __builtin_amdgcn_global_load_lds(                                        \
          (__attribute__((address_space(1))) void*)ga,                         \
          (__attribute__((address_space(3))) void*)&As[BUF][4096], 16, 0, 0);  \
    }                                                                          \
  }

#define PV_BLOAD(KS, BR)                                                       \
  {                                                                            \
    BR[0] = *(const bf16x8*)(Bp0 + (KS) * 16384);                              \
    BR[1] = *(const bf16x8*)(Bp1 + (KS) * 16384);                              \
    BR[2] = *(const bf16x8*)(Bp2 + (KS) * 16384);                              \
    BR[3] = *(const bf16x8*)(Bp3 + (KS) * 16384);                              \
  }

  // Steady outstanding at iter top (oldest first), wave 0 / waves 1-7:
  //   A(ks)2/1, B(ks)4, A(ks+1)2/1, B(ks+1)4, A(ks+2)2/1 = 14 / 11
  // -> WAITVM(12)/(10) retires exactly A(ks). Compiler waits cover B regs.
#define PV_ITER(KS, BUSE, BFILL)                                               \
  {                                                                            \
    if ((KS) < 70)       { if (w == 0) WAITVM(12); else WAITVM(10); }          \
    else if ((KS) == 70) { if (w == 0) WAITVM(10); else WAITVM(8); }           \
    else                 WAITVM(4);                                            \
    __builtin_amdgcn_sched_barrier(0);                                         \
    __builtin_amdgcn_s_barrier();                                              \
    bf16x8 af[9];                                                              \
    _Pragma("unroll")                                                          \
    for (int mi = 0; mi < 9; ++mi)                                             \
      af[mi] = *(const bf16x8*)&As[cur][(mi * 16 + lr) * 32 + sw];             \
    __builtin_amdgcn_s_setprio(1);                                             \
    _Pragma("unroll")                                                          \
    for (int mi = 0; mi < 9; ++mi)                                             \
      _Pragma("unroll")                                                        \
      for (int nj = 0; nj < 4; ++nj)                                           \
        acc[mi][nj] = __builtin_amdgcn_mfma_f32_16x16x32_bf16(                 \
            af[mi], BUSE[nj], acc[mi][nj], 0, 0, 0);                           \
    __builtin_amdgcn_s_setprio(0);                                             \
    __builtin_amdgcn_s_barrier();                                              \
    if ((KS) + 2 < 72) PV_BLOAD((KS) + 2, BFILL);                              \
    if ((KS) + 3 < 72) PVA_STAGE((KS) + 3, cur);                               \
    cur = (cur == 2) ? 0 : cur + 1;                                            \
  }

  bf16x8 bA[4], bB[4];
  PVA_STAGE(0, 0);
  PVA_STAGE(1, 1);
  PVA_STAGE(2, 2);
  PV_BLOAD(0, bA);
  PV_BLOAD(1, bB);
  int cur = 0;
  for (int ks = 0; ks < 72; ks += 2) {
    PV_ITER(ks, bA, bA);
    PV_ITER(ks + 1, bB, bB);
  }
#undef PV_ITER
#undef PV_BLOAD
#undef PVA_STAGE

  const float* lv = linv + (size_t)cb * 2304 + row0;
  short* Db = Dp + (size_t)bb * 2304 * 512;
  const int col = w * 64 + lr * 4;                 // permuted position
  const int coff = (col >> 5) * 4096 + (col & 31); // tiled col part
#pragma unroll
  for (int mi = 0; mi < 9; ++mi) {
#pragma unroll
    for (int r = 0; r < 4; ++r) {
      const int row = mi * 16 + lg * 4 + r;
      const float s = lv[row];
      const int R = row0 + row;
      s16x4 o = { f2bf(acc[mi][0][r] * s), f2bf(acc[mi][1][r] * s),
                  f2bf(acc[mi][2][r] * s), f2bf(acc[mi][3][r] * s) };
      // tiled oT store: off(R, col)
      *(s16x4*)(Db + (R >> 7) * 65536 + coff + (R & 127) * 32) = o;
    }
  }
}

// ---------------- launcher ---------------------------------------------------
extern "C" void kernel_launch(void* const* d_in, const int* in_sizes, int n_in,
                              void* d_out, int out_size, void* d_ws, size_t ws_size,
                              hipStream_t stream) {
  const float* x     = (const float*)d_in[0];
  const float* gamma = (const float*)d_in[1];
  const float* beta  = (const float*)d_in[2];
  const float* wq    = (const float*)d_in[3];
  const float* bq    = (const float*)d_in[4];
  const float* wk    = (const float*)d_in[5];
  // d_in[6] = bk: unused (per-row constant, cancels in softmax)
  const float* wv    = (const float*)d_in[7];
  const float* bv    = (const float*)d_in[8];
  const float* wo    = (const float*)d_in[9];
  const float* bo    = (const float*)d_in[10];

  char* ws = (char*)d_ws;
  float2* stats = (float2*)(ws + 0);
  short*  Wv    = (short*)(ws + 8192);
  short*  Wo    = (short*)(ws + 532480);
  short*  WkT   = (short*)(ws + 1056768);
  short*  WqT   = (short*)(ws + 1581056);
  short*  G     = (short*)(ws + 2105344);
  float*  g0    = (float*)(ws + 2629632);
  short*  yT    = (short*)(ws + 2631680);     //  36 MB  [B] tiled [18][16][128][32]
  short*  zoT   = (short*)(ws + 40380416);    //  36 MB  z/oT, tiled
  short*  vbuf  = (short*)(ws + 78129152);    //  36 MB  [B][72][32][16][32] tiled
  short*  Praw  = (short*)(ws + 115877888);   //  CH * 10,616,832 [b][18][2304][128]
  float*  out   = (float*)d_out;

  const size_t base = 115877888ull;
  const size_t per  = 10616832ull + 331776ull + 9216ull;  // Praw+Tsum+linv
  int CH = 16;
  if (ws_size < base + 16 * per) CH = (ws_size >= base + 8 * per) ? 8 : 4;
  float* Tsum = (float*)(ws + base + (size_t)CH * 10616832ull);
  float* linv = (float*)(ws + base + (size_t)CH * (10616832ull + 331776ull));

  const size_t sBN = (size_t)2304 * 512;

  prep_k<<<1024, 256, 0, stream>>>(wq, wk, wv, wo, Wv, Wo, WkT, WqT);
  g0_k<<<2, 256, 0, stream>>>(wk, bq, g0);
  gn_stats<<<512, 256, 0, stream>>>(x, stats);
  gn_norm_t<<<dim3(36, 8, 16), 256, 0, stream>>>(x, stats, gamma, beta, yT);
  // G[c'][c] = sum_o WkT[c'][o] * WqT[c][o]   (G stored tiled)
  gemm_k<2, false, false, false, true, 512, 512, 16><<<dim3(16, 1), 256, 0, stream>>>(
      WkT, 0, WqT, 0, G, 0, nullptr, nullptr, 512, 4, 0);
  // v[b][o][n] = sum_c Wv[o][c] * yT[b][n][c] + bv[o]  (vbuf-tiled store)
  gemm_k<3, true, true, true, false, 512, 512, 16><<<dim3(72, 16), 256, 0, stream>>>(
      Wv, 0, yT, sBN, vbuf, sBN, bv, nullptr, 2304, 4, 0);
  // z[b][i][c'] = sum_c yT[b][i][c] * G[c'][c] + g0[c']  (z stored tiled)
  gemm_k<0, false, true, true, true, 512, 512, 16><<<dim3(72, 16), 256, 0, stream>>>(
      yT, sBN, G, 0, zoT, sBN, g0, nullptr, 512, 18, 0);

  for (int b0 = 0; b0 < 16; b0 += CH) {
    const int n = (16 - b0 < CH) ? (16 - b0) : CH;
    gemm_s<<<dim3(324, n), 256, 0, stream>>>(zoT, yT, Praw, Tsum, b0);
    sum_k<<<(n * 2304 + 255) / 256, 256, 0, stream>>>(Tsum, linv, n * 2304);
    gemm_pv<<<dim3(16, n), 512, 0, stream>>>(Praw, linv, vbuf, zoT, b0);
  }
  // out[b][o][n] = sum_c Wo[o][c] * oT[b][n][c] + bo[o] + x[b][o][n]
  // (c-permutation on both Wo and oT cancels; both K-chunk-tiled)
  gemm_k<1, true, true, true, false, 512, 512, 16><<<dim3(72, 16), 256, 0, stream>>>(
      Wo, 0, zoT, sBN, out, (size_t)512 * 2304, bo, x, 2304, 4, 0);
}